// Round 1
// baseline (714.281 us; speedup 1.0000x reference)
//
#include <hip/hip_runtime.h>
#include <hip/hip_bf16.h>

// GCN 2-layer: h = relu(Anorm @ (x@W1) + b1); out = Anorm @ (h@W2) + b2
// Anorm = D^-1/2 (A + I) D^-1/2, deg from dst including self loops.
//
// Strategy: build CSR (by dst) on device each call (no float atomics),
// then pull-mode aggregation (one wave per node, register accumulators).

#define NTHREADS 256

// ---------- degree count ----------
__global__ void count_kernel(const int* __restrict__ dst, int* __restrict__ cnt, int e) {
    int i = blockIdx.x * blockDim.x + threadIdx.x;
    if (i < e) atomicAdd(&cnt[dst[i]], 1);
}

// ---------- exclusive scan, 3-phase (1024 elems per block) ----------
__global__ void scan_phase1(const int* __restrict__ cnt, int* __restrict__ start,
                            int* __restrict__ bsum, int n) {
    __shared__ int tsum[256];
    int t = threadIdx.x;
    int i0 = blockIdx.x * 1024 + t * 4;
    int v[4];
#pragma unroll
    for (int j = 0; j < 4; j++) v[j] = (i0 + j < n) ? cnt[i0 + j] : 0;
    int tot = v[0] + v[1] + v[2] + v[3];
    tsum[t] = tot;
    __syncthreads();
    int x = tot;
    for (int off = 1; off < 256; off <<= 1) {
        int y = (t >= off) ? tsum[t - off] : 0;
        __syncthreads();
        x += y;
        tsum[t] = x;
        __syncthreads();
    }
    int excl = x - tot;
#pragma unroll
    for (int j = 0; j < 4; j++) {
        if (i0 + j < n) start[i0 + j] = excl;
        excl += v[j];
    }
    if (t == 255) bsum[blockIdx.x] = x;
}

__global__ void scan_phase2(const int* __restrict__ bsum, int* __restrict__ boff, int nb) {
    __shared__ int buf[128];
    int t = threadIdx.x;
    int v = (t < nb) ? bsum[t] : 0;
    buf[t] = v;
    __syncthreads();
    int x = v;
    for (int off = 1; off < 128; off <<= 1) {
        int y = (t >= off) ? buf[t - off] : 0;
        __syncthreads();
        x += y;
        buf[t] = x;
        __syncthreads();
    }
    if (t < nb) boff[t] = x - v;
}

__global__ void scan_phase3(int* __restrict__ start, int* __restrict__ cursor,
                            const int* __restrict__ boff, int n) {
    int i = blockIdx.x * blockDim.x + threadIdx.x;
    if (i < n) {
        int s = start[i] + boff[i >> 10];
        start[i] = s;
        cursor[i] = s;
    }
}

// ---------- dinv = rsqrt(deg), deg = in-count + 1 (self loop) ----------
__global__ void dinv_kernel(const int* __restrict__ cnt, float* __restrict__ dinv, int n) {
    int i = blockIdx.x * blockDim.x + threadIdx.x;
    if (i < n) dinv[i] = rsqrtf((float)cnt[i] + 1.0f);
}

// ---------- CSR fill: col[] = src indices grouped by dst ----------
__global__ void fill_kernel(const int* __restrict__ src, const int* __restrict__ dst,
                            int* __restrict__ cursor, int* __restrict__ col, int e) {
    int i = blockIdx.x * blockDim.x + threadIdx.x;
    if (i < e) {
        int d = dst[i];
        int p = atomicAdd(&cursor[d], 1);
        col[p] = src[i];
    }
}

// ---------- f32 block GEMM: C[n,COLS] = X[n,128] @ W[128,COLS] ----------
// 256 threads, 4x4 register tile per thread -> ROWS = 4096/COLS rows/block.
// W staged fully in LDS; X tile staged transposed so both operands use b128 reads.
template <int COLS>
__global__ __launch_bounds__(256) void gemm_kernel(const float* __restrict__ X,
                                                   const float* __restrict__ W,
                                                   float* __restrict__ C, int n) {
    constexpr int ROWS = 4096 / COLS;  // 32 (COLS=128) or 64 (COLS=64)
    __shared__ float sW[128 * COLS];
    __shared__ float sXT[128 * ROWS];
    int t = threadIdx.x;
    int rbase = blockIdx.x * ROWS;

    // load W (coalesced float4)
    {
        float4* sW4 = (float4*)sW;
        const float4* W4 = (const float4*)W;
        constexpr int WV = 128 * COLS / 4;
        for (int i = t; i < WV; i += 256) sW4[i] = W4[i];
    }
    // load X tile, store transposed: sXT[k*ROWS + r]
    {
        int r = t % ROWS;
        int c0 = t / ROWS;                 // float4-chunk index along k
        constexpr int TC = 256 / ROWS;     // chunks strided by this
        int gr = rbase + r;
        for (int c = c0; c < 32; c += TC) {
            float4 v = make_float4(0.f, 0.f, 0.f, 0.f);
            if (gr < n) v = *(const float4*)(X + (size_t)gr * 128 + c * 4);
            int k = c * 4;
            sXT[(k + 0) * ROWS + r] = v.x;
            sXT[(k + 1) * ROWS + r] = v.y;
            sXT[(k + 2) * ROWS + r] = v.z;
            sXT[(k + 3) * ROWS + r] = v.w;
        }
    }
    __syncthreads();

    constexpr int CG = COLS / 4;   // col groups
    int cg = t % CG;
    int rg = t / CG;
    int c0 = cg * 4;
    int r0 = rg * 4;

    float acc[4][4] = {};
#pragma unroll 4
    for (int k = 0; k < 128; k++) {
        float4 xa = *(const float4*)&sXT[k * ROWS + r0];
        float4 wb = *(const float4*)&sW[k * COLS + c0];
        acc[0][0] += xa.x * wb.x; acc[0][1] += xa.x * wb.y; acc[0][2] += xa.x * wb.z; acc[0][3] += xa.x * wb.w;
        acc[1][0] += xa.y * wb.x; acc[1][1] += xa.y * wb.y; acc[1][2] += xa.y * wb.z; acc[1][3] += xa.y * wb.w;
        acc[2][0] += xa.z * wb.x; acc[2][1] += xa.z * wb.y; acc[2][2] += xa.z * wb.z; acc[2][3] += xa.z * wb.w;
        acc[3][0] += xa.w * wb.x; acc[3][1] += xa.w * wb.y; acc[3][2] += xa.w * wb.z; acc[3][3] += xa.w * wb.w;
    }
#pragma unroll
    for (int i = 0; i < 4; i++) {
        int rr = rbase + r0 + i;
        if (rr < n)
            *(float4*)&C[(size_t)rr * COLS + c0] =
                make_float4(acc[i][0], acc[i][1], acc[i][2], acc[i][3]);
    }
}

// ---------- pull-mode aggregation, D=128: one wave/node, float2 per lane ----------
template <bool RELU>
__global__ __launch_bounds__(256) void aggregate128(
    const float* __restrict__ h, const int* __restrict__ col,
    const int* __restrict__ start, const int* __restrict__ cnt,
    const float* __restrict__ dinv, const float* __restrict__ bias,
    float* __restrict__ out, int n) {
    int w = (int)((blockIdx.x * blockDim.x + threadIdx.x) >> 6);
    if (w >= n) return;
    int lane = threadIdx.x & 63;
    const float2* h2 = (const float2*)h;
    float di = dinv[w];
    // self loop: norm = di*di
    float2 acc = h2[(size_t)w * 64 + lane];
    float sw = di * di;
    acc.x *= sw; acc.y *= sw;
    int j = start[w];
    int e = j + cnt[w];
    for (; j < e; j++) {
        int s = col[j];
        float nw = dinv[s] * di;
        float2 v = h2[(size_t)s * 64 + lane];
        acc.x += v.x * nw;
        acc.y += v.y * nw;
    }
    acc.x += bias[lane * 2];
    acc.y += bias[lane * 2 + 1];
    if (RELU) {
        acc.x = fmaxf(acc.x, 0.f);
        acc.y = fmaxf(acc.y, 0.f);
    }
    ((float2*)out)[(size_t)w * 64 + lane] = acc;
}

// ---------- pull-mode aggregation, D=64: one wave/node, 1 float per lane ----------
template <bool RELU>
__global__ __launch_bounds__(256) void aggregate64(
    const float* __restrict__ h, const int* __restrict__ col,
    const int* __restrict__ start, const int* __restrict__ cnt,
    const float* __restrict__ dinv, const float* __restrict__ bias,
    float* __restrict__ out, int n) {
    int w = (int)((blockIdx.x * blockDim.x + threadIdx.x) >> 6);
    if (w >= n) return;
    int lane = threadIdx.x & 63;
    float di = dinv[w];
    float acc = h[(size_t)w * 64 + lane] * di * di;
    int j = start[w];
    int e = j + cnt[w];
    for (; j < e; j++) {
        int s = col[j];
        float nw = dinv[s] * di;
        acc += h[(size_t)s * 64 + lane] * nw;
    }
    acc += bias[lane];
    if (RELU) acc = fmaxf(acc, 0.f);
    out[(size_t)w * 64 + lane] = acc;
}

extern "C" void kernel_launch(void* const* d_in, const int* in_sizes, int n_in,
                              void* d_out, int out_size, void* d_ws, size_t ws_size,
                              hipStream_t stream) {
    const float* x = (const float*)d_in[0];
    const int* edge = (const int*)d_in[1];
    const float* W1 = (const float*)d_in[2];
    const float* b1 = (const float*)d_in[3];
    const float* W2 = (const float*)d_in[4];
    const float* b2 = (const float*)d_in[5];

    const int N = in_sizes[0] / 128;
    const int E = in_sizes[1] / 2;
    const int* src = edge;
    const int* dst = edge + E;

    // workspace carve-up (all chunks 16B-aligned for these sizes)
    char* p = (char*)d_ws;
    int* cnt = (int*)p;      p += (size_t)N * 4;
    int* start = (int*)p;    p += (size_t)N * 4;
    int* cursor = (int*)p;   p += (size_t)N * 4;
    int* bsum = (int*)p;     p += 512;
    int* boff = (int*)p;     p += 512;
    float* dinv = (float*)p; p += (size_t)N * 4;
    int* col = (int*)p;      p += (size_t)E * 4;
    float* h = (float*)p;    p += (size_t)N * 128 * 4;  // gemm1 out; reused for gemm2 out
    float* g = (float*)p;    p += (size_t)N * 128 * 4;  // layer-1 output (relu'd)

    float* out = (float*)d_out;

    const int nb = (N + 1023) / 1024;

    // CSR build
    hipMemsetAsync(cnt, 0, (size_t)N * 4, stream);
    count_kernel<<<(E + NTHREADS - 1) / NTHREADS, NTHREADS, 0, stream>>>(dst, cnt, E);
    scan_phase1<<<nb, 256, 0, stream>>>(cnt, start, bsum, N);
    scan_phase2<<<1, 128, 0, stream>>>(bsum, boff, nb);
    scan_phase3<<<(N + NTHREADS - 1) / NTHREADS, NTHREADS, 0, stream>>>(start, cursor, boff, N);
    dinv_kernel<<<(N + NTHREADS - 1) / NTHREADS, NTHREADS, 0, stream>>>(cnt, dinv, N);
    fill_kernel<<<(E + NTHREADS - 1) / NTHREADS, NTHREADS, 0, stream>>>(src, dst, cursor, col, E);

    // layer 1: h = x @ W1 ; g = relu(Anorm @ h + b1)
    gemm_kernel<128><<<(N + 31) / 32, 256, 0, stream>>>(x, W1, h, N);
    aggregate128<true><<<(N + 3) / 4, 256, 0, stream>>>(h, col, start, cnt, dinv, b1, g, N);

    // layer 2: h2 = g @ W2 (reuse h buffer) ; out = Anorm @ h2 + b2
    gemm_kernel<64><<<(N + 63) / 64, 256, 0, stream>>>(g, W2, h, N);
    aggregate64<false><<<(N + 3) / 4, 256, 0, stream>>>(h, col, start, cnt, dinv, b2, out, N);
}

// Round 3
// 465.000 us; speedup vs baseline: 1.5361x; 1.5361x over previous
//
#include <hip/hip_runtime.h>
#include <hip/hip_bf16.h>

// GCN 2-layer: h = relu(Anorm @ (x@W1) + b1); out = Anorm @ (h@W2) + b2
// Anorm = D^-1/2 (A + I) D^-1/2, deg from dst including self loops.
//
// R2 changes vs R1:
//  - CSR fill stores fused (src, norm) 8B records  -> no dinv gather in agg loop
//  - aggregation: cooperative record load + __shfl broadcast + 4x-unrolled
//    independent gathers (MLP=4 instead of serialized chain)
//  - GEMM outputs stored as bf16 (compute f32)     -> half gather bytes
// R3: fix compile error (cast ushort* -> uint* for packed bf16 store path)

#define NTHREADS 256

typedef unsigned int uint;
typedef unsigned short ushort;

__device__ __forceinline__ uint pack_bf16(float a, float b) {
    __hip_bfloat162 h = __float22bfloat162_rn(make_float2(a, b));
    return *reinterpret_cast<uint*>(&h);
}
__device__ __forceinline__ float bf16_lo(uint q) { return __uint_as_float(q << 16); }
__device__ __forceinline__ float bf16_hi(uint q) { return __uint_as_float(q & 0xffff0000u); }
__device__ __forceinline__ float bf16_one(ushort u) { return __uint_as_float(((uint)u) << 16); }

// ---------- degree count ----------
__global__ void count_kernel(const int* __restrict__ dst, int* __restrict__ cnt, int e) {
    int i = blockIdx.x * blockDim.x + threadIdx.x;
    if (i < e) atomicAdd(&cnt[dst[i]], 1);
}

// ---------- exclusive scan, 3-phase (1024 elems per block) ----------
__global__ void scan_phase1(const int* __restrict__ cnt, int* __restrict__ start,
                            int* __restrict__ bsum, int n) {
    __shared__ int tsum[256];
    int t = threadIdx.x;
    int i0 = blockIdx.x * 1024 + t * 4;
    int v[4];
#pragma unroll
    for (int j = 0; j < 4; j++) v[j] = (i0 + j < n) ? cnt[i0 + j] : 0;
    int tot = v[0] + v[1] + v[2] + v[3];
    tsum[t] = tot;
    __syncthreads();
    int x = tot;
    for (int off = 1; off < 256; off <<= 1) {
        int y = (t >= off) ? tsum[t - off] : 0;
        __syncthreads();
        x += y;
        tsum[t] = x;
        __syncthreads();
    }
    int excl = x - tot;
#pragma unroll
    for (int j = 0; j < 4; j++) {
        if (i0 + j < n) start[i0 + j] = excl;
        excl += v[j];
    }
    if (t == 255) bsum[blockIdx.x] = x;
}

__global__ void scan_phase2(const int* __restrict__ bsum, int* __restrict__ boff, int nb) {
    __shared__ int buf[128];
    int t = threadIdx.x;
    int v = (t < nb) ? bsum[t] : 0;
    buf[t] = v;
    __syncthreads();
    int x = v;
    for (int off = 1; off < 128; off <<= 1) {
        int y = (t >= off) ? buf[t - off] : 0;
        __syncthreads();
        x += y;
        buf[t] = x;
        __syncthreads();
    }
    if (t < nb) boff[t] = x - v;
}

__global__ void scan_phase3(int* __restrict__ start, int* __restrict__ cursor,
                            const int* __restrict__ boff, int n) {
    int i = blockIdx.x * blockDim.x + threadIdx.x;
    if (i < n) {
        int s = start[i] + boff[i >> 10];
        start[i] = s;
        cursor[i] = s;
    }
}

// ---------- dinv = rsqrt(deg), deg = in-count + 1 (self loop) ----------
__global__ void dinv_kernel(const int* __restrict__ cnt, float* __restrict__ dinv, int n) {
    int i = blockIdx.x * blockDim.x + threadIdx.x;
    if (i < n) dinv[i] = rsqrtf((float)cnt[i] + 1.0f);
}

// ---------- CSR fill: rec[] = (src, dinv[src]*dinv[dst]) grouped by dst ----------
__global__ void fill_kernel(const int* __restrict__ src, const int* __restrict__ dst,
                            int* __restrict__ cursor, const float* __restrict__ dinv,
                            int2* __restrict__ rec, int e) {
    int i = blockIdx.x * blockDim.x + threadIdx.x;
    if (i < e) {
        int d = dst[i];
        int s = src[i];
        int p = atomicAdd(&cursor[d], 1);
        float nw = dinv[s] * dinv[d];
        rec[p] = make_int2(s, __float_as_int(nw));
    }
}

// ---------- f32 block GEMM, bf16 output: Cq[n,COLS] = X[n,128] @ W[128,COLS] ----------
// 256 threads, 4x4 register tile per thread -> ROWS = 4096/COLS rows/block.
template <int COLS>
__global__ __launch_bounds__(256) void gemm_kernel(const float* __restrict__ X,
                                                   const float* __restrict__ W,
                                                   uint* __restrict__ Cq, int n) {
    constexpr int ROWS = 4096 / COLS;  // 32 (COLS=128) or 64 (COLS=64)
    __shared__ float sW[128 * COLS];
    __shared__ float sXT[128 * ROWS];
    int t = threadIdx.x;
    int rbase = blockIdx.x * ROWS;

    {
        float4* sW4 = (float4*)sW;
        const float4* W4 = (const float4*)W;
        constexpr int WV = 128 * COLS / 4;
        for (int i = t; i < WV; i += 256) sW4[i] = W4[i];
    }
    {
        int r = t % ROWS;
        int c0 = t / ROWS;
        constexpr int TC = 256 / ROWS;
        int gr = rbase + r;
        for (int c = c0; c < 32; c += TC) {
            float4 v = make_float4(0.f, 0.f, 0.f, 0.f);
            if (gr < n) v = *(const float4*)(X + (size_t)gr * 128 + c * 4);
            int k = c * 4;
            sXT[(k + 0) * ROWS + r] = v.x;
            sXT[(k + 1) * ROWS + r] = v.y;
            sXT[(k + 2) * ROWS + r] = v.z;
            sXT[(k + 3) * ROWS + r] = v.w;
        }
    }
    __syncthreads();

    constexpr int CG = COLS / 4;
    int cg = t % CG;
    int rg = t / CG;
    int c0 = cg * 4;
    int r0 = rg * 4;

    float acc[4][4] = {};
#pragma unroll 4
    for (int k = 0; k < 128; k++) {
        float4 xa = *(const float4*)&sXT[k * ROWS + r0];
        float4 wb = *(const float4*)&sW[k * COLS + c0];
        acc[0][0] += xa.x * wb.x; acc[0][1] += xa.x * wb.y; acc[0][2] += xa.x * wb.z; acc[0][3] += xa.x * wb.w;
        acc[1][0] += xa.y * wb.x; acc[1][1] += xa.y * wb.y; acc[1][2] += xa.y * wb.z; acc[1][3] += xa.y * wb.w;
        acc[2][0] += xa.z * wb.x; acc[2][1] += xa.z * wb.y; acc[2][2] += xa.z * wb.z; acc[2][3] += xa.z * wb.w;
        acc[3][0] += xa.w * wb.x; acc[3][1] += xa.w * wb.y; acc[3][2] += xa.w * wb.z; acc[3][3] += xa.w * wb.w;
    }
#pragma unroll
    for (int i = 0; i < 4; i++) {
        int rr = rbase + r0 + i;
        if (rr < n) {
            uint2 pk;
            pk.x = pack_bf16(acc[i][0], acc[i][1]);
            pk.y = pack_bf16(acc[i][2], acc[i][3]);
            *(uint2*)&Cq[((size_t)rr * COLS + c0) / 2] = pk;
        }
    }
}

// ---------- pull aggregation, D=128 (bf16 in, f32 out): one wave/node ----------
template <bool RELU>
__global__ __launch_bounds__(256) void aggregate128q(
    const uint* __restrict__ hq, const int2* __restrict__ rec,
    const int* __restrict__ start, const int* __restrict__ cnt,
    const float* __restrict__ dinv, const float* __restrict__ bias,
    float* __restrict__ out, int n) {
    int w0 = (int)((blockIdx.x * blockDim.x + threadIdx.x) >> 6);
    int w = __builtin_amdgcn_readfirstlane(w0);
    if (w >= n) return;
    int lane = threadIdx.x & 63;

    float di = dinv[w];
    float sw = di * di;
    uint qs = hq[(size_t)w * 64 + lane];
    float accx = bf16_lo(qs) * sw;
    float accy = bf16_hi(qs) * sw;

    int j0 = start[w];
    int deg = cnt[w];
    for (int base = 0; base < deg; base += 64) {
        int m = min(64, deg - base);
        int2 r = make_int2(0, 0);
        if (lane < m) r = rec[j0 + base + lane];
        int t = 0;
        for (; t + 4 <= m; t += 4) {
            int s0 = __shfl(r.x, t + 0), s1 = __shfl(r.x, t + 1);
            int s2 = __shfl(r.x, t + 2), s3 = __shfl(r.x, t + 3);
            float w0f = __int_as_float(__shfl(r.y, t + 0));
            float w1f = __int_as_float(__shfl(r.y, t + 1));
            float w2f = __int_as_float(__shfl(r.y, t + 2));
            float w3f = __int_as_float(__shfl(r.y, t + 3));
            uint q0 = hq[(size_t)s0 * 64 + lane];
            uint q1 = hq[(size_t)s1 * 64 + lane];
            uint q2 = hq[(size_t)s2 * 64 + lane];
            uint q3 = hq[(size_t)s3 * 64 + lane];
            accx += bf16_lo(q0) * w0f; accy += bf16_hi(q0) * w0f;
            accx += bf16_lo(q1) * w1f; accy += bf16_hi(q1) * w1f;
            accx += bf16_lo(q2) * w2f; accy += bf16_hi(q2) * w2f;
            accx += bf16_lo(q3) * w3f; accy += bf16_hi(q3) * w3f;
        }
        for (; t < m; t++) {
            int s = __shfl(r.x, t);
            float nw = __int_as_float(__shfl(r.y, t));
            uint q = hq[(size_t)s * 64 + lane];
            accx += bf16_lo(q) * nw;
            accy += bf16_hi(q) * nw;
        }
    }

    float2 o;
    o.x = accx + bias[lane * 2];
    o.y = accy + bias[lane * 2 + 1];
    if (RELU) {
        o.x = fmaxf(o.x, 0.f);
        o.y = fmaxf(o.y, 0.f);
    }
    ((float2*)out)[(size_t)w * 64 + lane] = o;
}

// ---------- pull aggregation, D=64 (bf16 in, f32 out): one wave/node ----------
template <bool RELU>
__global__ __launch_bounds__(256) void aggregate64q(
    const ushort* __restrict__ hq, const int2* __restrict__ rec,
    const int* __restrict__ start, const int* __restrict__ cnt,
    const float* __restrict__ dinv, const float* __restrict__ bias,
    float* __restrict__ out, int n) {
    int w0 = (int)((blockIdx.x * blockDim.x + threadIdx.x) >> 6);
    int w = __builtin_amdgcn_readfirstlane(w0);
    if (w >= n) return;
    int lane = threadIdx.x & 63;

    float di = dinv[w];
    float acc = bf16_one(hq[(size_t)w * 64 + lane]) * di * di;

    int j0 = start[w];
    int deg = cnt[w];
    for (int base = 0; base < deg; base += 64) {
        int m = min(64, deg - base);
        int2 r = make_int2(0, 0);
        if (lane < m) r = rec[j0 + base + lane];
        int t = 0;
        for (; t + 4 <= m; t += 4) {
            int s0 = __shfl(r.x, t + 0), s1 = __shfl(r.x, t + 1);
            int s2 = __shfl(r.x, t + 2), s3 = __shfl(r.x, t + 3);
            float w0f = __int_as_float(__shfl(r.y, t + 0));
            float w1f = __int_as_float(__shfl(r.y, t + 1));
            float w2f = __int_as_float(__shfl(r.y, t + 2));
            float w3f = __int_as_float(__shfl(r.y, t + 3));
            float v0 = bf16_one(hq[(size_t)s0 * 64 + lane]);
            float v1 = bf16_one(hq[(size_t)s1 * 64 + lane]);
            float v2 = bf16_one(hq[(size_t)s2 * 64 + lane]);
            float v3 = bf16_one(hq[(size_t)s3 * 64 + lane]);
            acc += v0 * w0f + v1 * w1f + v2 * w2f + v3 * w3f;
        }
        for (; t < m; t++) {
            int s = __shfl(r.x, t);
            float nw = __int_as_float(__shfl(r.y, t));
            acc += bf16_one(hq[(size_t)s * 64 + lane]) * nw;
        }
    }

    acc += bias[lane];
    if (RELU) acc = fmaxf(acc, 0.f);
    out[(size_t)w * 64 + lane] = acc;
}

extern "C" void kernel_launch(void* const* d_in, const int* in_sizes, int n_in,
                              void* d_out, int out_size, void* d_ws, size_t ws_size,
                              hipStream_t stream) {
    const float* x = (const float*)d_in[0];
    const int* edge = (const int*)d_in[1];
    const float* W1 = (const float*)d_in[2];
    const float* b1 = (const float*)d_in[3];
    const float* W2 = (const float*)d_in[4];
    const float* b2 = (const float*)d_in[5];

    const int N = in_sizes[0] / 128;
    const int E = in_sizes[1] / 2;
    const int* src = edge;
    const int* dst = edge + E;

    // workspace carve-up (all chunks 16B-aligned for these sizes)
    char* p = (char*)d_ws;
    int* cnt = (int*)p;       p += (size_t)N * 4;
    int* startA = (int*)p;    p += (size_t)N * 4;
    int* cursor = (int*)p;    p += (size_t)N * 4;
    int* bsum = (int*)p;      p += 512;
    int* boff = (int*)p;      p += 512;
    float* dinv = (float*)p;  p += (size_t)N * 4;
    int2* rec = (int2*)p;     p += (size_t)E * 8;       // (src, norm) per edge
    uint* hq = (uint*)p;      p += (size_t)N * 64 * 4;  // h = x@W1, bf16 pairs
    float* g = (float*)p;     p += (size_t)N * 128 * 4; // relu(agg) f32
    ushort* h2q = (ushort*)p; p += (size_t)N * 64 * 2;  // h2 = g@W2, bf16

    float* out = (float*)d_out;
    const int nb = (N + 1023) / 1024;

    // CSR build
    (void)hipMemsetAsync(cnt, 0, (size_t)N * 4, stream);
    count_kernel<<<(E + NTHREADS - 1) / NTHREADS, NTHREADS, 0, stream>>>(dst, cnt, E);
    scan_phase1<<<nb, 256, 0, stream>>>(cnt, startA, bsum, N);
    scan_phase2<<<1, 128, 0, stream>>>(bsum, boff, nb);
    scan_phase3<<<(N + NTHREADS - 1) / NTHREADS, NTHREADS, 0, stream>>>(startA, cursor, boff, N);
    dinv_kernel<<<(N + NTHREADS - 1) / NTHREADS, NTHREADS, 0, stream>>>(cnt, dinv, N);
    fill_kernel<<<(E + NTHREADS - 1) / NTHREADS, NTHREADS, 0, stream>>>(src, dst, cursor, dinv, rec, E);

    // layer 1: h = x @ W1 (bf16 out); g = relu(Anorm @ h + b1)
    gemm_kernel<128><<<(N + 31) / 32, 256, 0, stream>>>(x, W1, hq, N);
    aggregate128q<true><<<(N + 3) / 4, 256, 0, stream>>>(hq, rec, startA, cnt, dinv, b1, g, N);

    // layer 2: h2 = g @ W2 (bf16 out); out = Anorm @ h2 + b2
    gemm_kernel<64><<<(N + 63) / 64, 256, 0, stream>>>(g, W2, (uint*)h2q, N);
    aggregate64q<false><<<(N + 3) / 4, 256, 0, stream>>>(h2q, rec, startA, cnt, dinv, b2, out, N);
}

// Round 4
// 415.409 us; speedup vs baseline: 1.7195x; 1.1194x over previous
//
#include <hip/hip_runtime.h>
#include <hip/hip_bf16.h>

// GCN 2-layer: h = relu(Anorm @ (x@W1) + b1); out = Anorm @ (h@W2) + b2
// R4 changes vs R3:
//  - both GEMMs -> bf16 MFMA (mfma_f32_16x16x32_bf16), LDS-staged with
//    16B-chunk XOR swizzle (conflict-free ds_read_b128 fragments)
//  - operand-swap (W^T as A-operand) so each lane holds 4 consecutive
//    output cols -> packed 8B bf16 stores
//  - aggregate128 writes g as packed bf16 (fused convert for GEMM2 input)

#define NTHREADS 256

typedef unsigned int uint;
typedef unsigned short ushort;
typedef __attribute__((ext_vector_type(8))) short short8;
typedef __attribute__((ext_vector_type(4))) float floatx4;

__device__ __forceinline__ uint pack_bf16(float a, float b) {
    __hip_bfloat162 h = __float22bfloat162_rn(make_float2(a, b));
    return *reinterpret_cast<uint*>(&h);
}
__device__ __forceinline__ float bf16_lo(uint q) { return __uint_as_float(q << 16); }
__device__ __forceinline__ float bf16_hi(uint q) { return __uint_as_float(q & 0xffff0000u); }
__device__ __forceinline__ float bf16_one(ushort u) { return __uint_as_float(((uint)u) << 16); }

// ---------- degree count ----------
__global__ void count_kernel(const int* __restrict__ dst, int* __restrict__ cnt, int e) {
    int i = blockIdx.x * blockDim.x + threadIdx.x;
    if (i < e) atomicAdd(&cnt[dst[i]], 1);
}

// ---------- exclusive scan, 3-phase (1024 elems per block) ----------
__global__ void scan_phase1(const int* __restrict__ cnt, int* __restrict__ start,
                            int* __restrict__ bsum, int n) {
    __shared__ int tsum[256];
    int t = threadIdx.x;
    int i0 = blockIdx.x * 1024 + t * 4;
    int v[4];
#pragma unroll
    for (int j = 0; j < 4; j++) v[j] = (i0 + j < n) ? cnt[i0 + j] : 0;
    int tot = v[0] + v[1] + v[2] + v[3];
    tsum[t] = tot;
    __syncthreads();
    int x = tot;
    for (int off = 1; off < 256; off <<= 1) {
        int y = (t >= off) ? tsum[t - off] : 0;
        __syncthreads();
        x += y;
        tsum[t] = x;
        __syncthreads();
    }
    int excl = x - tot;
#pragma unroll
    for (int j = 0; j < 4; j++) {
        if (i0 + j < n) start[i0 + j] = excl;
        excl += v[j];
    }
    if (t == 255) bsum[blockIdx.x] = x;
}

__global__ void scan_phase2(const int* __restrict__ bsum, int* __restrict__ boff, int nb) {
    __shared__ int buf[128];
    int t = threadIdx.x;
    int v = (t < nb) ? bsum[t] : 0;
    buf[t] = v;
    __syncthreads();
    int x = v;
    for (int off = 1; off < 128; off <<= 1) {
        int y = (t >= off) ? buf[t - off] : 0;
        __syncthreads();
        x += y;
        buf[t] = x;
        __syncthreads();
    }
    if (t < nb) boff[t] = x - v;
}

__global__ void scan_phase3(int* __restrict__ start, int* __restrict__ cursor,
                            const int* __restrict__ boff, int n) {
    int i = blockIdx.x * blockDim.x + threadIdx.x;
    if (i < n) {
        int s = start[i] + boff[i >> 10];
        start[i] = s;
        cursor[i] = s;
    }
}

// ---------- dinv = rsqrt(deg), deg = in-count + 1 (self loop) ----------
__global__ void dinv_kernel(const int* __restrict__ cnt, float* __restrict__ dinv, int n) {
    int i = blockIdx.x * blockDim.x + threadIdx.x;
    if (i < n) dinv[i] = rsqrtf((float)cnt[i] + 1.0f);
}

// ---------- CSR fill: rec[] = (src, dinv[src]*dinv[dst]) grouped by dst ----------
__global__ void fill_kernel(const int* __restrict__ src, const int* __restrict__ dst,
                            int* __restrict__ cursor, const float* __restrict__ dinv,
                            int2* __restrict__ rec, int e) {
    int i = blockIdx.x * blockDim.x + threadIdx.x;
    if (i < e) {
        int d = dst[i];
        int s = src[i];
        int p = atomicAdd(&cursor[d], 1);
        float nw = dinv[s] * dinv[d];
        rec[p] = make_int2(s, __float_as_int(nw));
    }
}

// ---------- bf16 MFMA GEMM: Cq[n,COLS](bf16) = X[n,128] @ W[128,COLS] ----------
// Block: 64 rows x COLS, 256 threads = 4 waves (wave w -> rows w*16..w*16+15).
// X staged in LDS as bf16 (converted if f32 input), W staged transposed bf16.
// 16B-chunk XOR swizzle on both -> conflict-free ds_read_b128 fragments.
// mfma(A=W^T-frag, B=X-frag): D col(lane&15)=X-row m, D rows(q*4+r)=out cols.
template <int COLS, bool XF32>
__global__ __launch_bounds__(256) void gemm_mfma(const void* __restrict__ Xv,
                                                 const float* __restrict__ W,
                                                 uint* __restrict__ Cq, int n) {
    __shared__ ushort sX[64 * 128];
    __shared__ ushort sWT[COLS * 128];
    int t = threadIdx.x;
    int rbase = blockIdx.x * 64;

    if (XF32) {
        const float* X = (const float*)Xv;
#pragma unroll
        for (int i = 0; i < 8; i++) {
            int f = t + 256 * i;   // 2048 float4 units: 64 rows x 32
            int r = f >> 5;
            int c4 = f & 31;
            float4 v = make_float4(0.f, 0.f, 0.f, 0.f);
            int gr = rbase + r;
            if (gr < n) v = *(const float4*)(X + (size_t)gr * 128 + c4 * 4);
            uint lo = pack_bf16(v.x, v.y);
            uint hi = pack_bf16(v.z, v.w);
            int chunk = c4 >> 1;
            int sub = (c4 & 1) * 4;
            int off = r * 128 + (((chunk ^ (r & 15)) << 3) + sub);
            *(uint2*)&sX[off] = make_uint2(lo, hi);
        }
    } else {
        const ushort* X = (const ushort*)Xv;
#pragma unroll
        for (int i = 0; i < 4; i++) {
            int f = t + 256 * i;   // 1024 uint4 units: 64 rows x 16 chunks
            int r = f >> 4;
            int chunk = f & 15;
            uint4 v = make_uint4(0, 0, 0, 0);
            int gr = rbase + r;
            if (gr < n) v = *(const uint4*)(X + (size_t)gr * 128 + chunk * 8);
            int off = r * 128 + ((chunk ^ (r & 15)) << 3);
            *(uint4*)&sX[off] = v;
        }
    }
    {
        constexpr int UNITS = 64 * (COLS / 4);   // (k-pair, n-quad)
        constexpr int PER_T = UNITS / 256;
#pragma unroll
        for (int i = 0; i < PER_T; i++) {
            int u = t + 256 * i;
            int kp = u / (COLS / 4);
            int n4 = u % (COLS / 4);
            int k = kp * 2;
            float4 w0 = *(const float4*)(W + (size_t)k * COLS + n4 * 4);
            float4 w1 = *(const float4*)(W + (size_t)(k + 1) * COLS + n4 * 4);
            int chunk = k >> 3;
            int sub = k & 7;   // even
            const float* a0 = (const float*)&w0;
            const float* a1 = (const float*)&w1;
#pragma unroll
            for (int j = 0; j < 4; j++) {
                int nn = n4 * 4 + j;
                uint pk = pack_bf16(a0[j], a1[j]);
                int off = nn * 128 + (((chunk ^ (nn & 15)) << 3) + sub);
                *(uint*)&sWT[off] = pk;
            }
        }
    }
    __syncthreads();

    int lane = t & 63;
    int wave = t >> 6;
    int m = lane & 15;
    int q = lane >> 4;
    int r0 = wave * 16;

    floatx4 acc[COLS / 16];
#pragma unroll
    for (int c = 0; c < COLS / 16; c++) acc[c] = (floatx4){0.f, 0.f, 0.f, 0.f};

#pragma unroll
    for (int ks = 0; ks < 4; ks++) {
        int rr = r0 + m;
        int ca = (ks * 4 + q) ^ (rr & 15);
        short8 afrag = *(const short8*)&sX[rr * 128 + (ca << 3)];
#pragma unroll
        for (int c = 0; c < COLS / 16; c++) {
            int nn = c * 16 + m;
            int cb = (ks * 4 + q) ^ (nn & 15);
            short8 bfrag = *(const short8*)&sWT[nn * 128 + (cb << 3)];
            acc[c] = __builtin_amdgcn_mfma_f32_16x16x32_bf16(bfrag, afrag, acc[c], 0, 0, 0);
        }
    }

    int gr = rbase + r0 + m;
    if (gr < n) {
#pragma unroll
        for (int c = 0; c < COLS / 16; c++) {
            uint2 pk;
            pk.x = pack_bf16(acc[c][0], acc[c][1]);
            pk.y = pack_bf16(acc[c][2], acc[c][3]);
            *(uint2*)&Cq[(size_t)gr * (COLS / 2) + c * 8 + q * 2] = pk;
        }
    }
}

// ---------- pull aggregation, D=128 (bf16 in, bf16 out + relu): one wave/node ----------
__global__ __launch_bounds__(256) void aggregate128q(
    const uint* __restrict__ hq, const int2* __restrict__ rec,
    const int* __restrict__ start, const int* __restrict__ cnt,
    const float* __restrict__ dinv, const float* __restrict__ bias,
    uint* __restrict__ outq, int n) {
    int w0 = (int)((blockIdx.x * blockDim.x + threadIdx.x) >> 6);
    int w = __builtin_amdgcn_readfirstlane(w0);
    if (w >= n) return;
    int lane = threadIdx.x & 63;

    float di = dinv[w];
    float sw = di * di;
    uint qs = hq[(size_t)w * 64 + lane];
    float accx = bf16_lo(qs) * sw;
    float accy = bf16_hi(qs) * sw;

    int j0 = start[w];
    int deg = cnt[w];
    for (int base = 0; base < deg; base += 64) {
        int m = min(64, deg - base);
        int2 r = make_int2(0, 0);
        if (lane < m) r = rec[j0 + base + lane];
        int t = 0;
        for (; t + 4 <= m; t += 4) {
            int s0 = __shfl(r.x, t + 0), s1 = __shfl(r.x, t + 1);
            int s2 = __shfl(r.x, t + 2), s3 = __shfl(r.x, t + 3);
            float w0f = __int_as_float(__shfl(r.y, t + 0));
            float w1f = __int_as_float(__shfl(r.y, t + 1));
            float w2f = __int_as_float(__shfl(r.y, t + 2));
            float w3f = __int_as_float(__shfl(r.y, t + 3));
            uint q0 = hq[(size_t)s0 * 64 + lane];
            uint q1 = hq[(size_t)s1 * 64 + lane];
            uint q2 = hq[(size_t)s2 * 64 + lane];
            uint q3 = hq[(size_t)s3 * 64 + lane];
            accx += bf16_lo(q0) * w0f; accy += bf16_hi(q0) * w0f;
            accx += bf16_lo(q1) * w1f; accy += bf16_hi(q1) * w1f;
            accx += bf16_lo(q2) * w2f; accy += bf16_hi(q2) * w2f;
            accx += bf16_lo(q3) * w3f; accy += bf16_hi(q3) * w3f;
        }
        for (; t < m; t++) {
            int s = __shfl(r.x, t);
            float nw = __int_as_float(__shfl(r.y, t));
            uint q = hq[(size_t)s * 64 + lane];
            accx += bf16_lo(q) * nw;
            accy += bf16_hi(q) * nw;
        }
    }

    float ox = fmaxf(accx + bias[lane * 2], 0.f);
    float oy = fmaxf(accy + bias[lane * 2 + 1], 0.f);
    outq[(size_t)w * 64 + lane] = pack_bf16(ox, oy);
}

// ---------- pull aggregation, D=64 (bf16 in, f32 out): one wave/node ----------
__global__ __launch_bounds__(256) void aggregate64q(
    const ushort* __restrict__ hq, const int2* __restrict__ rec,
    const int* __restrict__ start, const int* __restrict__ cnt,
    const float* __restrict__ dinv, const float* __restrict__ bias,
    float* __restrict__ out, int n) {
    int w0 = (int)((blockIdx.x * blockDim.x + threadIdx.x) >> 6);
    int w = __builtin_amdgcn_readfirstlane(w0);
    if (w >= n) return;
    int lane = threadIdx.x & 63;

    float di = dinv[w];
    float acc = bf16_one(hq[(size_t)w * 64 + lane]) * di * di;

    int j0 = start[w];
    int deg = cnt[w];
    for (int base = 0; base < deg; base += 64) {
        int m = min(64, deg - base);
        int2 r = make_int2(0, 0);
        if (lane < m) r = rec[j0 + base + lane];
        int t = 0;
        for (; t + 4 <= m; t += 4) {
            int s0 = __shfl(r.x, t + 0), s1 = __shfl(r.x, t + 1);
            int s2 = __shfl(r.x, t + 2), s3 = __shfl(r.x, t + 3);
            float w0f = __int_as_float(__shfl(r.y, t + 0));
            float w1f = __int_as_float(__shfl(r.y, t + 1));
            float w2f = __int_as_float(__shfl(r.y, t + 2));
            float w3f = __int_as_float(__shfl(r.y, t + 3));
            float v0 = bf16_one(hq[(size_t)s0 * 64 + lane]);
            float v1 = bf16_one(hq[(size_t)s1 * 64 + lane]);
            float v2 = bf16_one(hq[(size_t)s2 * 64 + lane]);
            float v3 = bf16_one(hq[(size_t)s3 * 64 + lane]);
            acc += v0 * w0f + v1 * w1f + v2 * w2f + v3 * w3f;
        }
        for (; t < m; t++) {
            int s = __shfl(r.x, t);
            float nw = __int_as_float(__shfl(r.y, t));
            acc += bf16_one(hq[(size_t)s * 64 + lane]) * nw;
        }
    }

    acc += bias[lane];
    out[(size_t)w * 64 + lane] = acc;
}

extern "C" void kernel_launch(void* const* d_in, const int* in_sizes, int n_in,
                              void* d_out, int out_size, void* d_ws, size_t ws_size,
                              hipStream_t stream) {
    const float* x = (const float*)d_in[0];
    const int* edge = (const int*)d_in[1];
    const float* W1 = (const float*)d_in[2];
    const float* b1 = (const float*)d_in[3];
    const float* W2 = (const float*)d_in[4];
    const float* b2 = (const float*)d_in[5];

    const int N = in_sizes[0] / 128;
    const int E = in_sizes[1] / 2;
    const int* src = edge;
    const int* dst = edge + E;

    // workspace carve-up (all chunks 16B-aligned for these sizes)
    char* p = (char*)d_ws;
    int* cnt = (int*)p;       p += (size_t)N * 4;
    int* startA = (int*)p;    p += (size_t)N * 4;
    int* cursor = (int*)p;    p += (size_t)N * 4;
    int* bsum = (int*)p;      p += 512;
    int* boff = (int*)p;      p += 512;
    float* dinv = (float*)p;  p += (size_t)N * 4;
    int2* rec = (int2*)p;     p += (size_t)E * 8;       // (src, norm) per edge
    uint* hq = (uint*)p;      p += (size_t)N * 64 * 4;  // h = x@W1, bf16 pairs
    uint* g = (uint*)p;       p += (size_t)N * 64 * 4;  // relu(agg) bf16 pairs
    ushort* h2q = (ushort*)p; p += (size_t)N * 64 * 2;  // h2 = g@W2, bf16

    float* out = (float*)d_out;
    const int nb = (N + 1023) / 1024;

    // CSR build
    (void)hipMemsetAsync(cnt, 0, (size_t)N * 4, stream);
    count_kernel<<<(E + NTHREADS - 1) / NTHREADS, NTHREADS, 0, stream>>>(dst, cnt, E);
    scan_phase1<<<nb, 256, 0, stream>>>(cnt, startA, bsum, N);
    scan_phase2<<<1, 128, 0, stream>>>(bsum, boff, nb);
    scan_phase3<<<(N + NTHREADS - 1) / NTHREADS, NTHREADS, 0, stream>>>(startA, cursor, boff, N);
    dinv_kernel<<<(N + NTHREADS - 1) / NTHREADS, NTHREADS, 0, stream>>>(cnt, dinv, N);
    fill_kernel<<<(E + NTHREADS - 1) / NTHREADS, NTHREADS, 0, stream>>>(src, dst, cursor, dinv, rec, E);

    const int gblocks = (N + 63) / 64;

    // layer 1: h = x @ W1 (bf16); g = relu(Anorm @ h + b1) (bf16)
    gemm_mfma<128, true><<<gblocks, 256, 0, stream>>>(x, W1, hq, N);
    aggregate128q<<<(N + 3) / 4, 256, 0, stream>>>(hq, rec, startA, cnt, dinv, b1, g, N);

    // layer 2: h2 = g @ W2 (bf16); out = Anorm @ h2 + b2
    gemm_mfma<64, false><<<gblocks, 256, 0, stream>>>(g, W2, (uint*)h2q, N);
    aggregate64q<<<(N + 3) / 4, 256, 0, stream>>>(h2q, rec, startA, cnt, dinv, b2, out, N);
}

// Round 5
// 401.819 us; speedup vs baseline: 1.7776x; 1.0338x over previous
//
#include <hip/hip_runtime.h>
#include <hip/hip_bf16.h>

// GCN 2-layer: h = relu(Anorm @ (x@W1) + b1); out = Anorm @ (h@W2) + b2
// R5 changes vs R4:
//  - fill_kernel (76us, 101MB scattered writes) -> two-level bucketed fill:
//    coarse 512-node bucket partition (LDS hist, contiguous segment writes)
//    then fine per-node scatter inside L2-hot 64KB windows.
//  - aggregation gather unroll 4 -> 8 (avg deg 16, more MLP)

#define NTHREADS 256
#define BSH 9                 // bucket = dst >> 9 (512 nodes/bucket)
#define NBMAX 256

typedef unsigned int uint;
typedef unsigned short ushort;
typedef __attribute__((ext_vector_type(8))) short short8;
typedef __attribute__((ext_vector_type(4))) float floatx4;

__device__ __forceinline__ uint pack_bf16(float a, float b) {
    __hip_bfloat162 h = __float22bfloat162_rn(make_float2(a, b));
    return *reinterpret_cast<uint*>(&h);
}
__device__ __forceinline__ float bf16_lo(uint q) { return __uint_as_float(q << 16); }
__device__ __forceinline__ float bf16_hi(uint q) { return __uint_as_float(q & 0xffff0000u); }
__device__ __forceinline__ float bf16_one(ushort u) { return __uint_as_float(((uint)u) << 16); }

// ---------- per-node degree + coarse bucket histogram ----------
// 2048 edges per block: LDS hist flushed once -> ~196 bucket atomics/block.
__global__ __launch_bounds__(256) void count_bucket_kernel(
    const int* __restrict__ dst, int* __restrict__ cnt,
    int* __restrict__ bcnt, int e, int nb) {
    __shared__ int hist[NBMAX];
    int t = threadIdx.x;
    for (int b = t; b < nb; b += 256) hist[b] = 0;
    __syncthreads();
    int e0 = blockIdx.x * 2048;
#pragma unroll
    for (int i = 0; i < 8; i++) {
        int gi = e0 + t + i * 256;
        if (gi < e) {
            int d = dst[gi];
            atomicAdd(&cnt[d], 1);
            atomicAdd(&hist[d >> BSH], 1);
        }
    }
    __syncthreads();
    for (int b = t; b < nb; b += 256) {
        int v = hist[b];
        if (v) atomicAdd(&bcnt[b], v);
    }
}

// ---------- exclusive scan, 3-phase (1024 elems per block) ----------
__global__ void scan_phase1(const int* __restrict__ cnt, int* __restrict__ start,
                            int* __restrict__ bsum, int n) {
    __shared__ int tsum[256];
    int t = threadIdx.x;
    int i0 = blockIdx.x * 1024 + t * 4;
    int v[4];
#pragma unroll
    for (int j = 0; j < 4; j++) v[j] = (i0 + j < n) ? cnt[i0 + j] : 0;
    int tot = v[0] + v[1] + v[2] + v[3];
    tsum[t] = tot;
    __syncthreads();
    int x = tot;
    for (int off = 1; off < 256; off <<= 1) {
        int y = (t >= off) ? tsum[t - off] : 0;
        __syncthreads();
        x += y;
        tsum[t] = x;
        __syncthreads();
    }
    int excl = x - tot;
#pragma unroll
    for (int j = 0; j < 4; j++) {
        if (i0 + j < n) start[i0 + j] = excl;
        excl += v[j];
    }
    if (t == 255) bsum[blockIdx.x] = x;
}

__global__ void scan_phase2(const int* __restrict__ bsum, int* __restrict__ boff, int nb) {
    __shared__ int buf[128];
    int t = threadIdx.x;
    int v = (t < nb) ? bsum[t] : 0;
    buf[t] = v;
    __syncthreads();
    int x = v;
    for (int off = 1; off < 128; off <<= 1) {
        int y = (t >= off) ? buf[t - off] : 0;
        __syncthreads();
        x += y;
        buf[t] = x;
        __syncthreads();
    }
    if (t < nb) boff[t] = x - v;
}

__global__ void scan_phase3(int* __restrict__ start, int* __restrict__ cursor,
                            const int* __restrict__ boff, int n) {
    int i = blockIdx.x * blockDim.x + threadIdx.x;
    if (i < n) {
        int s = start[i] + boff[i >> 10];
        start[i] = s;
        cursor[i] = s;
    }
}

// ---------- bucket scan (nb <= 256, single block) ----------
__global__ void bucket_scan(const int* __restrict__ bcnt, int* __restrict__ bstart,
                            int* __restrict__ bcursor, int nb) {
    __shared__ int buf[NBMAX];
    int t = threadIdx.x;
    int v = (t < nb) ? bcnt[t] : 0;
    buf[t] = v;
    __syncthreads();
    int x = v;
    for (int off = 1; off < NBMAX; off <<= 1) {
        int y = (t >= off) ? buf[t - off] : 0;
        __syncthreads();
        x += y;
        buf[t] = x;
        __syncthreads();
    }
    if (t < nb) {
        bstart[t] = x - v;
        bcursor[t] = x - v;
    }
}

// ---------- dinv = rsqrt(deg), deg = in-count + 1 (self loop) ----------
__global__ void dinv_kernel(const int* __restrict__ cnt, float* __restrict__ dinv, int n) {
    int i = blockIdx.x * blockDim.x + threadIdx.x;
    if (i < n) dinv[i] = rsqrtf((float)cnt[i] + 1.0f);
}

// ---------- coarse partition: staged[] = (src,dst) grouped by bucket ----------
__global__ __launch_bounds__(256) void partition_kernel(
    const int* __restrict__ src, const int* __restrict__ dst,
    int* __restrict__ bcursor, int2* __restrict__ staged, int e, int nb) {
    __shared__ int eS[2048];
    __shared__ int eD[2048];
    __shared__ int hist[NBMAX];
    __shared__ int base[NBMAX];
    int t = threadIdx.x;
    int e0 = blockIdx.x * 2048;

    for (int b = t; b < nb; b += 256) hist[b] = 0;
    __syncthreads();
#pragma unroll
    for (int i = 0; i < 8; i++) {
        int li = t + i * 256;
        int gi = e0 + li;
        int s = 0, d = -1;
        if (gi < e) { s = src[gi]; d = dst[gi]; }
        eS[li] = s;
        eD[li] = d;
        if (d >= 0) atomicAdd(&hist[d >> BSH], 1);
    }
    __syncthreads();
    for (int b = t; b < nb; b += 256) {
        int v = hist[b];
        base[b] = v ? atomicAdd(&bcursor[b], v) : 0;
        hist[b] = 0;   // reset for rank pass
    }
    __syncthreads();
#pragma unroll
    for (int i = 0; i < 8; i++) {
        int li = t + i * 256;
        int d = eD[li];
        if (d >= 0) {
            int b = d >> BSH;
            int r = atomicAdd(&hist[b], 1);
            staged[base[b] + r] = make_int2(eS[li], d);
        }
    }
}

// ---------- fine fill inside hot bucket window: rec[] = (src, norm) by dst ----------
__global__ __launch_bounds__(512) void fine_fill_kernel(
    const int2* __restrict__ staged, const int* __restrict__ bstart,
    const int* __restrict__ bcnt, int* __restrict__ cursor,
    const float* __restrict__ dinv, int2* __restrict__ rec) {
    int b = blockIdx.x;
    int s0 = bstart[b];
    int m = bcnt[b];
    for (int i = threadIdx.x; i < m; i += 512) {
        int2 ed = staged[s0 + i];
        int p = atomicAdd(&cursor[ed.y], 1);
        float nw = dinv[ed.x] * dinv[ed.y];
        rec[p] = make_int2(ed.x, __float_as_int(nw));
    }
}

// ---------- bf16 MFMA GEMM: Cq[n,COLS](bf16) = X[n,128] @ W[128,COLS] ----------
template <int COLS, bool XF32>
__global__ __launch_bounds__(256) void gemm_mfma(const void* __restrict__ Xv,
                                                 const float* __restrict__ W,
                                                 uint* __restrict__ Cq, int n) {
    __shared__ ushort sX[64 * 128];
    __shared__ ushort sWT[COLS * 128];
    int t = threadIdx.x;
    int rbase = blockIdx.x * 64;

    if (XF32) {
        const float* X = (const float*)Xv;
#pragma unroll
        for (int i = 0; i < 8; i++) {
            int f = t + 256 * i;
            int r = f >> 5;
            int c4 = f & 31;
            float4 v = make_float4(0.f, 0.f, 0.f, 0.f);
            int gr = rbase + r;
            if (gr < n) v = *(const float4*)(X + (size_t)gr * 128 + c4 * 4);
            uint lo = pack_bf16(v.x, v.y);
            uint hi = pack_bf16(v.z, v.w);
            int chunk = c4 >> 1;
            int sub = (c4 & 1) * 4;
            int off = r * 128 + (((chunk ^ (r & 15)) << 3) + sub);
            *(uint2*)&sX[off] = make_uint2(lo, hi);
        }
    } else {
        const ushort* X = (const ushort*)Xv;
#pragma unroll
        for (int i = 0; i < 4; i++) {
            int f = t + 256 * i;
            int r = f >> 4;
            int chunk = f & 15;
            uint4 v = make_uint4(0, 0, 0, 0);
            int gr = rbase + r;
            if (gr < n) v = *(const uint4*)(X + (size_t)gr * 128 + chunk * 8);
            int off = r * 128 + ((chunk ^ (r & 15)) << 3);
            *(uint4*)&sX[off] = v;
        }
    }
    {
        constexpr int UNITS = 64 * (COLS / 4);
        constexpr int PER_T = UNITS / 256;
#pragma unroll
        for (int i = 0; i < PER_T; i++) {
            int u = t + 256 * i;
            int kp = u / (COLS / 4);
            int n4 = u % (COLS / 4);
            int k = kp * 2;
            float4 w0 = *(const float4*)(W + (size_t)k * COLS + n4 * 4);
            float4 w1 = *(const float4*)(W + (size_t)(k + 1) * COLS + n4 * 4);
            int chunk = k >> 3;
            int sub = k & 7;
            const float* a0 = (const float*)&w0;
            const float* a1 = (const float*)&w1;
#pragma unroll
            for (int j = 0; j < 4; j++) {
                int nn = n4 * 4 + j;
                uint pk = pack_bf16(a0[j], a1[j]);
                int off = nn * 128 + (((chunk ^ (nn & 15)) << 3) + sub);
                *(uint*)&sWT[off] = pk;
            }
        }
    }
    __syncthreads();

    int lane = t & 63;
    int wave = t >> 6;
    int m = lane & 15;
    int q = lane >> 4;
    int r0 = wave * 16;

    floatx4 acc[COLS / 16];
#pragma unroll
    for (int c = 0; c < COLS / 16; c++) acc[c] = (floatx4){0.f, 0.f, 0.f, 0.f};

#pragma unroll
    for (int ks = 0; ks < 4; ks++) {
        int rr = r0 + m;
        int ca = (ks * 4 + q) ^ (rr & 15);
        short8 afrag = *(const short8*)&sX[rr * 128 + (ca << 3)];
#pragma unroll
        for (int c = 0; c < COLS / 16; c++) {
            int nn = c * 16 + m;
            int cb = (ks * 4 + q) ^ (nn & 15);
            short8 bfrag = *(const short8*)&sWT[nn * 128 + (cb << 3)];
            acc[c] = __builtin_amdgcn_mfma_f32_16x16x32_bf16(bfrag, afrag, acc[c], 0, 0, 0);
        }
    }

    int gr = rbase + r0 + m;
    if (gr < n) {
#pragma unroll
        for (int c = 0; c < COLS / 16; c++) {
            uint2 pk;
            pk.x = pack_bf16(acc[c][0], acc[c][1]);
            pk.y = pack_bf16(acc[c][2], acc[c][3]);
            *(uint2*)&Cq[(size_t)gr * (COLS / 2) + c * 8 + q * 2] = pk;
        }
    }
}

// ---------- pull aggregation, D=128 (bf16 in, bf16 out + relu): one wave/node ----------
__global__ __launch_bounds__(256) void aggregate128q(
    const uint* __restrict__ hq, const int2* __restrict__ rec,
    const int* __restrict__ start, const int* __restrict__ cnt,
    const float* __restrict__ dinv, const float* __restrict__ bias,
    uint* __restrict__ outq, int n) {
    int w0 = (int)((blockIdx.x * blockDim.x + threadIdx.x) >> 6);
    int w = __builtin_amdgcn_readfirstlane(w0);
    if (w >= n) return;
    int lane = threadIdx.x & 63;

    float di = dinv[w];
    float sw = di * di;
    uint qs = hq[(size_t)w * 64 + lane];
    float accx = bf16_lo(qs) * sw;
    float accy = bf16_hi(qs) * sw;

    int j0 = start[w];
    int deg = cnt[w];
    for (int base = 0; base < deg; base += 64) {
        int m = min(64, deg - base);
        int2 r = make_int2(0, 0);
        if (lane < m) r = rec[j0 + base + lane];
        int t = 0;
        for (; t + 8 <= m; t += 8) {
            int s[8];
            float wf[8];
            uint q[8];
#pragma unroll
            for (int u = 0; u < 8; u++) {
                s[u] = __shfl(r.x, t + u);
                wf[u] = __int_as_float(__shfl(r.y, t + u));
            }
#pragma unroll
            for (int u = 0; u < 8; u++) q[u] = hq[(size_t)s[u] * 64 + lane];
#pragma unroll
            for (int u = 0; u < 8; u++) {
                accx += bf16_lo(q[u]) * wf[u];
                accy += bf16_hi(q[u]) * wf[u];
            }
        }
        for (; t + 4 <= m; t += 4) {
            int s0 = __shfl(r.x, t + 0), s1 = __shfl(r.x, t + 1);
            int s2 = __shfl(r.x, t + 2), s3 = __shfl(r.x, t + 3);
            float w0f = __int_as_float(__shfl(r.y, t + 0));
            float w1f = __int_as_float(__shfl(r.y, t + 1));
            float w2f = __int_as_float(__shfl(r.y, t + 2));
            float w3f = __int_as_float(__shfl(r.y, t + 3));
            uint q0 = hq[(size_t)s0 * 64 + lane];
            uint q1 = hq[(size_t)s1 * 64 + lane];
            uint q2 = hq[(size_t)s2 * 64 + lane];
            uint q3 = hq[(size_t)s3 * 64 + lane];
            accx += bf16_lo(q0) * w0f; accy += bf16_hi(q0) * w0f;
            accx += bf16_lo(q1) * w1f; accy += bf16_hi(q1) * w1f;
            accx += bf16_lo(q2) * w2f; accy += bf16_hi(q2) * w2f;
            accx += bf16_lo(q3) * w3f; accy += bf16_hi(q3) * w3f;
        }
        for (; t < m; t++) {
            int s = __shfl(r.x, t);
            float nw = __int_as_float(__shfl(r.y, t));
            uint q = hq[(size_t)s * 64 + lane];
            accx += bf16_lo(q) * nw;
            accy += bf16_hi(q) * nw;
        }
    }

    float ox = fmaxf(accx + bias[lane * 2], 0.f);
    float oy = fmaxf(accy + bias[lane * 2 + 1], 0.f);
    outq[(size_t)w * 64 + lane] = pack_bf16(ox, oy);
}

// ---------- pull aggregation, D=64 (bf16 in, f32 out): one wave/node ----------
__global__ __launch_bounds__(256) void aggregate64q(
    const ushort* __restrict__ hq, const int2* __restrict__ rec,
    const int* __restrict__ start, const int* __restrict__ cnt,
    const float* __restrict__ dinv, const float* __restrict__ bias,
    float* __restrict__ out, int n) {
    int w0 = (int)((blockIdx.x * blockDim.x + threadIdx.x) >> 6);
    int w = __builtin_amdgcn_readfirstlane(w0);
    if (w >= n) return;
    int lane = threadIdx.x & 63;

    float di = dinv[w];
    float acc = bf16_one(hq[(size_t)w * 64 + lane]) * di * di;

    int j0 = start[w];
    int deg = cnt[w];
    for (int base = 0; base < deg; base += 64) {
        int m = min(64, deg - base);
        int2 r = make_int2(0, 0);
        if (lane < m) r = rec[j0 + base + lane];
        int t = 0;
        for (; t + 8 <= m; t += 8) {
            int s[8];
            float wf[8];
            float v[8];
#pragma unroll
            for (int u = 0; u < 8; u++) {
                s[u] = __shfl(r.x, t + u);
                wf[u] = __int_as_float(__shfl(r.y, t + u));
            }
#pragma unroll
            for (int u = 0; u < 8; u++) v[u] = bf16_one(hq[(size_t)s[u] * 64 + lane]);
#pragma unroll
            for (int u = 0; u < 8; u++) acc += v[u] * wf[u];
        }
        for (; t + 4 <= m; t += 4) {
            int s0 = __shfl(r.x, t + 0), s1 = __shfl(r.x, t + 1);
            int s2 = __shfl(r.x, t + 2), s3 = __shfl(r.x, t + 3);
            float w0f = __int_as_float(__shfl(r.y, t + 0));
            float w1f = __int_as_float(__shfl(r.y, t + 1));
            float w2f = __int_as_float(__shfl(r.y, t + 2));
            float w3f = __int_as_float(__shfl(r.y, t + 3));
            float v0 = bf16_one(hq[(size_t)s0 * 64 + lane]);
            float v1 = bf16_one(hq[(size_t)s1 * 64 + lane]);
            float v2 = bf16_one(hq[(size_t)s2 * 64 + lane]);
            float v3 = bf16_one(hq[(size_t)s3 * 64 + lane]);
            acc += v0 * w0f + v1 * w1f + v2 * w2f + v3 * w3f;
        }
        for (; t < m; t++) {
            int s = __shfl(r.x, t);
            float nw = __int_as_float(__shfl(r.y, t));
            acc += bf16_one(hq[(size_t)s * 64 + lane]) * nw;
        }
    }

    acc += bias[lane];
    out[(size_t)w * 64 + lane] = acc;
}

extern "C" void kernel_launch(void* const* d_in, const int* in_sizes, int n_in,
                              void* d_out, int out_size, void* d_ws, size_t ws_size,
                              hipStream_t stream) {
    const float* x = (const float*)d_in[0];
    const int* edge = (const int*)d_in[1];
    const float* W1 = (const float*)d_in[2];
    const float* b1 = (const float*)d_in[3];
    const float* W2 = (const float*)d_in[4];
    const float* b2 = (const float*)d_in[5];

    const int N = in_sizes[0] / 128;
    const int E = in_sizes[1] / 2;
    const int* src = edge;
    const int* dst = edge + E;
    const int NB = (N + (1 << BSH) - 1) >> BSH;   // coarse buckets (<= 256)

    // workspace carve-up (all chunks 16B-aligned for these sizes)
    char* p = (char*)d_ws;
    int* cnt = (int*)p;       p += (size_t)N * 4;
    int* bcnt = (int*)p;      p += NBMAX * 4;     // cnt+bcnt zeroed together
    int* startA = (int*)p;    p += (size_t)N * 4;
    int* cursor = (int*)p;    p += (size_t)N * 4;
    int* bsum = (int*)p;      p += 512;
    int* boff = (int*)p;      p += 512;
    int* bstart = (int*)p;    p += NBMAX * 4;
    int* bcursor = (int*)p;   p += NBMAX * 4;
    float* dinv = (float*)p;  p += (size_t)N * 4;
    int2* rec = (int2*)p;     p += (size_t)E * 8;       // (src, norm) per edge
    uint* hq = (uint*)p;      p += (size_t)N * 64 * 4;  // h = x@W1, bf16 pairs
    uint* g = (uint*)p;       p += (size_t)N * 64 * 4;  // relu(agg) bf16 pairs
    ushort* h2q = (ushort*)p; p += (size_t)N * 64 * 2;  // h2 = g@W2, bf16

    // staged (src,dst) records alias g: dead before aggregate128q writes g
    int2* staged = (int2*)g;

    float* out = (float*)d_out;
    const int nb1024 = (N + 1023) / 1024;
    const int eblocks = (E + 2047) / 2048;

    // CSR build (two-level bucketed)
    (void)hipMemsetAsync(cnt, 0, (size_t)N * 4 + NBMAX * 4, stream);
    count_bucket_kernel<<<eblocks, 256, 0, stream>>>(dst, cnt, bcnt, E, NB);
    scan_phase1<<<nb1024, 256, 0, stream>>>(cnt, startA, bsum, N);
    scan_phase2<<<1, 128, 0, stream>>>(bsum, boff, nb1024);
    scan_phase3<<<(N + NTHREADS - 1) / NTHREADS, NTHREADS, 0, stream>>>(startA, cursor, boff, N);
    bucket_scan<<<1, NBMAX, 0, stream>>>(bcnt, bstart, bcursor, NB);
    dinv_kernel<<<(N + NTHREADS - 1) / NTHREADS, NTHREADS, 0, stream>>>(cnt, dinv, N);
    partition_kernel<<<eblocks, 256, 0, stream>>>(src, dst, bcursor, staged, E, NB);
    fine_fill_kernel<<<NB, 512, 0, stream>>>(staged, bstart, bcnt, cursor, dinv, rec);

    const int gblocks = (N + 63) / 64;

    // layer 1: h = x @ W1 (bf16); g = relu(Anorm @ h + b1) (bf16)
    gemm_mfma<128, true><<<gblocks, 256, 0, stream>>>(x, W1, hq, N);
    aggregate128q<<<(N + 3) / 4, 256, 0, stream>>>(hq, rec, startA, cnt, dinv, b1, g, N);

    // layer 2: h2 = g @ W2 (bf16); out = Anorm @ h2 + b2
    gemm_mfma<64, false><<<gblocks, 256, 0, stream>>>(g, W2, (uint*)h2q, N);
    aggregate64q<<<(N + 3) / 4, 256, 0, stream>>>(h2q, rec, startA, cnt, dinv, b2, out, N);
}

// Round 6
// 329.917 us; speedup vs baseline: 2.1650x; 1.2179x over previous
//
#include <hip/hip_runtime.h>
#include <hip/hip_bf16.h>

// GCN 2-layer: h = relu(Anorm @ (x@W1) + b1); out = Anorm @ (h@W2) + b2
// R6 changes vs R5:
//  - eliminate ALL per-node global atomics: bucket_hist counts only the
//    196 coarse buckets; per-node degree/prefix/dinv computed per-bucket
//    in LDS (fine_count), per-node cursors in LDS (fine_fill).
//  - scan_phase1/2/3 + dinv_kernel dispatches deleted (folded into
//    bucket_scan + fine_count).

#define NTHREADS 256
#define BSH 9                 // bucket = dst >> 9 (512 nodes/bucket)
#define NBMAX 256

typedef unsigned int uint;
typedef unsigned short ushort;
typedef __attribute__((ext_vector_type(8))) short short8;
typedef __attribute__((ext_vector_type(4))) float floatx4;

__device__ __forceinline__ uint pack_bf16(float a, float b) {
    __hip_bfloat162 h = __float22bfloat162_rn(make_float2(a, b));
    return *reinterpret_cast<uint*>(&h);
}
__device__ __forceinline__ float bf16_lo(uint q) { return __uint_as_float(q << 16); }
__device__ __forceinline__ float bf16_hi(uint q) { return __uint_as_float(q & 0xffff0000u); }
__device__ __forceinline__ float bf16_one(ushort u) { return __uint_as_float(((uint)u) << 16); }

// ---------- coarse bucket histogram only (no per-node atomics) ----------
__global__ __launch_bounds__(256) void bucket_hist_kernel(
    const int* __restrict__ dst, int* __restrict__ bcnt, int e, int nb) {
    __shared__ int hist[NBMAX];
    int t = threadIdx.x;
    for (int b = t; b < nb; b += 256) hist[b] = 0;
    __syncthreads();
    int e0 = blockIdx.x * 2048;
#pragma unroll
    for (int i = 0; i < 8; i++) {
        int gi = e0 + t + i * 256;
        if (gi < e) atomicAdd(&hist[dst[gi] >> BSH], 1);
    }
    __syncthreads();
    for (int b = t; b < nb; b += 256) {
        int v = hist[b];
        if (v) atomicAdd(&bcnt[b], v);
    }
}

// ---------- bucket scan (nb <= 256, single block) ----------
__global__ void bucket_scan(const int* __restrict__ bcnt, int* __restrict__ bstart,
                            int* __restrict__ bcursor, int nb) {
    __shared__ int buf[NBMAX];
    int t = threadIdx.x;
    int v = (t < nb) ? bcnt[t] : 0;
    buf[t] = v;
    __syncthreads();
    int x = v;
    for (int off = 1; off < NBMAX; off <<= 1) {
        int y = (t >= off) ? buf[t - off] : 0;
        __syncthreads();
        x += y;
        buf[t] = x;
        __syncthreads();
    }
    if (t < nb) {
        bstart[t] = x - v;
        bcursor[t] = x - v;
    }
}

// ---------- coarse partition: staged[] = (src,dst) grouped by bucket ----------
__global__ __launch_bounds__(256) void partition_kernel(
    const int* __restrict__ src, const int* __restrict__ dst,
    int* __restrict__ bcursor, int2* __restrict__ staged, int e, int nb) {
    __shared__ int eS[2048];
    __shared__ int eD[2048];
    __shared__ int hist[NBMAX];
    __shared__ int base[NBMAX];
    int t = threadIdx.x;
    int e0 = blockIdx.x * 2048;

    for (int b = t; b < nb; b += 256) hist[b] = 0;
    __syncthreads();
#pragma unroll
    for (int i = 0; i < 8; i++) {
        int li = t + i * 256;
        int gi = e0 + li;
        int s = 0, d = -1;
        if (gi < e) { s = src[gi]; d = dst[gi]; }
        eS[li] = s;
        eD[li] = d;
        if (d >= 0) atomicAdd(&hist[d >> BSH], 1);
    }
    __syncthreads();
    for (int b = t; b < nb; b += 256) {
        int v = hist[b];
        base[b] = v ? atomicAdd(&bcursor[b], v) : 0;
        hist[b] = 0;   // reset for rank pass
    }
    __syncthreads();
#pragma unroll
    for (int i = 0; i < 8; i++) {
        int li = t + i * 256;
        int d = eD[li];
        if (d >= 0) {
            int b = d >> BSH;
            int r = atomicAdd(&hist[b], 1);
            staged[base[b] + r] = make_int2(eS[li], d);
        }
    }
}

// ---------- per-bucket: LDS degree count + scan -> cnt/startA/dinv ----------
__global__ __launch_bounds__(256) void fine_count_kernel(
    const int2* __restrict__ staged, const int* __restrict__ bstart,
    const int* __restrict__ bcnt, int* __restrict__ cnt,
    int* __restrict__ startA, float* __restrict__ dinv, int n) {
    __shared__ int lcnt[512];
    __shared__ int tsum[256];
    int b = blockIdx.x;
    int t = threadIdx.x;
    lcnt[t] = 0;
    lcnt[t + 256] = 0;
    __syncthreads();
    int s0 = bstart[b];
    int m = bcnt[b];
    for (int i = t; i < m; i += 256)
        atomicAdd(&lcnt[staged[s0 + i].y & 511], 1);
    __syncthreads();
    int v0 = lcnt[2 * t];
    int v1 = lcnt[2 * t + 1];
    int tot = v0 + v1;
    tsum[t] = tot;
    __syncthreads();
    int x = tot;
    for (int off = 1; off < 256; off <<= 1) {
        int y = (t >= off) ? tsum[t - off] : 0;
        __syncthreads();
        x += y;
        tsum[t] = x;
        __syncthreads();
    }
    int excl = x - tot;
    int node = (b << BSH) + 2 * t;
    if (node < n) {
        cnt[node] = v0;
        startA[node] = s0 + excl;
        dinv[node] = rsqrtf((float)v0 + 1.0f);
    }
    if (node + 1 < n) {
        cnt[node + 1] = v1;
        startA[node + 1] = s0 + excl + v0;
        dinv[node + 1] = rsqrtf((float)v1 + 1.0f);
    }
}

// ---------- per-bucket fill in hot window: rec[] = (src, norm) by dst ----------
__global__ __launch_bounds__(256) void fine_fill_kernel(
    const int2* __restrict__ staged, const int* __restrict__ bstart,
    const int* __restrict__ bcnt, const int* __restrict__ startA,
    const float* __restrict__ dinv, int2* __restrict__ rec, int n) {
    __shared__ int lcur[512];
    __shared__ float ldv[512];
    int b = blockIdx.x;
    int t = threadIdx.x;
    int nb0 = b << BSH;
    for (int i = t; i < 512; i += 256) {
        int node = nb0 + i;
        lcur[i] = (node < n) ? startA[node] : 0;
        ldv[i] = (node < n) ? dinv[node] : 0.f;
    }
    __syncthreads();
    int s0 = bstart[b];
    int m = bcnt[b];
    for (int i = t; i < m; i += 256) {
        int2 ed = staged[s0 + i];
        int li = ed.y & 511;
        int pos = atomicAdd(&lcur[li], 1);
        float nw = dinv[ed.x] * ldv[li];
        rec[pos] = make_int2(ed.x, __float_as_int(nw));
    }
}

// ---------- bf16 MFMA GEMM: Cq[n,COLS](bf16) = X[n,128] @ W[128,COLS] ----------
template <int COLS, bool XF32>
__global__ __launch_bounds__(256) void gemm_mfma(const void* __restrict__ Xv,
                                                 const float* __restrict__ W,
                                                 uint* __restrict__ Cq, int n) {
    __shared__ ushort sX[64 * 128];
    __shared__ ushort sWT[COLS * 128];
    int t = threadIdx.x;
    int rbase = blockIdx.x * 64;

    if (XF32) {
        const float* X = (const float*)Xv;
#pragma unroll
        for (int i = 0; i < 8; i++) {
            int f = t + 256 * i;
            int r = f >> 5;
            int c4 = f & 31;
            float4 v = make_float4(0.f, 0.f, 0.f, 0.f);
            int gr = rbase + r;
            if (gr < n) v = *(const float4*)(X + (size_t)gr * 128 + c4 * 4);
            uint lo = pack_bf16(v.x, v.y);
            uint hi = pack_bf16(v.z, v.w);
            int chunk = c4 >> 1;
            int sub = (c4 & 1) * 4;
            int off = r * 128 + (((chunk ^ (r & 15)) << 3) + sub);
            *(uint2*)&sX[off] = make_uint2(lo, hi);
        }
    } else {
        const ushort* X = (const ushort*)Xv;
#pragma unroll
        for (int i = 0; i < 4; i++) {
            int f = t + 256 * i;
            int r = f >> 4;
            int chunk = f & 15;
            uint4 v = make_uint4(0, 0, 0, 0);
            int gr = rbase + r;
            if (gr < n) v = *(const uint4*)(X + (size_t)gr * 128 + chunk * 8);
            int off = r * 128 + ((chunk ^ (r & 15)) << 3);
            *(uint4*)&sX[off] = v;
        }
    }
    {
        constexpr int UNITS = 64 * (COLS / 4);
        constexpr int PER_T = UNITS / 256;
#pragma unroll
        for (int i = 0; i < PER_T; i++) {
            int u = t + 256 * i;
            int kp = u / (COLS / 4);
            int n4 = u % (COLS / 4);
            int k = kp * 2;
            float4 w0 = *(const float4*)(W + (size_t)k * COLS + n4 * 4);
            float4 w1 = *(const float4*)(W + (size_t)(k + 1) * COLS + n4 * 4);
            int chunk = k >> 3;
            int sub = k & 7;
            const float* a0 = (const float*)&w0;
            const float* a1 = (const float*)&w1;
#pragma unroll
            for (int j = 0; j < 4; j++) {
                int nn = n4 * 4 + j;
                uint pk = pack_bf16(a0[j], a1[j]);
                int off = nn * 128 + (((chunk ^ (nn & 15)) << 3) + sub);
                *(uint*)&sWT[off] = pk;
            }
        }
    }
    __syncthreads();

    int lane = t & 63;
    int wave = t >> 6;
    int m = lane & 15;
    int q = lane >> 4;
    int r0 = wave * 16;

    floatx4 acc[COLS / 16];
#pragma unroll
    for (int c = 0; c < COLS / 16; c++) acc[c] = (floatx4){0.f, 0.f, 0.f, 0.f};

#pragma unroll
    for (int ks = 0; ks < 4; ks++) {
        int rr = r0 + m;
        int ca = (ks * 4 + q) ^ (rr & 15);
        short8 afrag = *(const short8*)&sX[rr * 128 + (ca << 3)];
#pragma unroll
        for (int c = 0; c < COLS / 16; c++) {
            int nn = c * 16 + m;
            int cb = (ks * 4 + q) ^ (nn & 15);
            short8 bfrag = *(const short8*)&sWT[nn * 128 + (cb << 3)];
            acc[c] = __builtin_amdgcn_mfma_f32_16x16x32_bf16(bfrag, afrag, acc[c], 0, 0, 0);
        }
    }

    int gr = rbase + r0 + m;
    if (gr < n) {
#pragma unroll
        for (int c = 0; c < COLS / 16; c++) {
            uint2 pk;
            pk.x = pack_bf16(acc[c][0], acc[c][1]);
            pk.y = pack_bf16(acc[c][2], acc[c][3]);
            *(uint2*)&Cq[(size_t)gr * (COLS / 2) + c * 8 + q * 2] = pk;
        }
    }
}

// ---------- pull aggregation, D=128 (bf16 in, bf16 out + relu): one wave/node ----------
__global__ __launch_bounds__(256) void aggregate128q(
    const uint* __restrict__ hq, const int2* __restrict__ rec,
    const int* __restrict__ start, const int* __restrict__ cnt,
    const float* __restrict__ dinv, const float* __restrict__ bias,
    uint* __restrict__ outq, int n) {
    int w0 = (int)((blockIdx.x * blockDim.x + threadIdx.x) >> 6);
    int w = __builtin_amdgcn_readfirstlane(w0);
    if (w >= n) return;
    int lane = threadIdx.x & 63;

    float di = dinv[w];
    float sw = di * di;
    uint qs = hq[(size_t)w * 64 + lane];
    float accx = bf16_lo(qs) * sw;
    float accy = bf16_hi(qs) * sw;

    int j0 = start[w];
    int deg = cnt[w];
    for (int base = 0; base < deg; base += 64) {
        int m = min(64, deg - base);
        int2 r = make_int2(0, 0);
        if (lane < m) r = rec[j0 + base + lane];
        int t = 0;
        for (; t + 8 <= m; t += 8) {
            int s[8];
            float wf[8];
            uint q[8];
#pragma unroll
            for (int u = 0; u < 8; u++) {
                s[u] = __shfl(r.x, t + u);
                wf[u] = __int_as_float(__shfl(r.y, t + u));
            }
#pragma unroll
            for (int u = 0; u < 8; u++) q[u] = hq[(size_t)s[u] * 64 + lane];
#pragma unroll
            for (int u = 0; u < 8; u++) {
                accx += bf16_lo(q[u]) * wf[u];
                accy += bf16_hi(q[u]) * wf[u];
            }
        }
        for (; t + 4 <= m; t += 4) {
            int s0 = __shfl(r.x, t + 0), s1 = __shfl(r.x, t + 1);
            int s2 = __shfl(r.x, t + 2), s3 = __shfl(r.x, t + 3);
            float w0f = __int_as_float(__shfl(r.y, t + 0));
            float w1f = __int_as_float(__shfl(r.y, t + 1));
            float w2f = __int_as_float(__shfl(r.y, t + 2));
            float w3f = __int_as_float(__shfl(r.y, t + 3));
            uint q0 = hq[(size_t)s0 * 64 + lane];
            uint q1 = hq[(size_t)s1 * 64 + lane];
            uint q2 = hq[(size_t)s2 * 64 + lane];
            uint q3 = hq[(size_t)s3 * 64 + lane];
            accx += bf16_lo(q0) * w0f; accy += bf16_hi(q0) * w0f;
            accx += bf16_lo(q1) * w1f; accy += bf16_hi(q1) * w1f;
            accx += bf16_lo(q2) * w2f; accy += bf16_hi(q2) * w2f;
            accx += bf16_lo(q3) * w3f; accy += bf16_hi(q3) * w3f;
        }
        for (; t < m; t++) {
            int s = __shfl(r.x, t);
            float nw = __int_as_float(__shfl(r.y, t));
            uint q = hq[(size_t)s * 64 + lane];
            accx += bf16_lo(q) * nw;
            accy += bf16_hi(q) * nw;
        }
    }

    float ox = fmaxf(accx + bias[lane * 2], 0.f);
    float oy = fmaxf(accy + bias[lane * 2 + 1], 0.f);
    outq[(size_t)w * 64 + lane] = pack_bf16(ox, oy);
}

// ---------- pull aggregation, D=64 (bf16 in, f32 out): one wave/node ----------
__global__ __launch_bounds__(256) void aggregate64q(
    const ushort* __restrict__ hq, const int2* __restrict__ rec,
    const int* __restrict__ start, const int* __restrict__ cnt,
    const float* __restrict__ dinv, const float* __restrict__ bias,
    float* __restrict__ out, int n) {
    int w0 = (int)((blockIdx.x * blockDim.x + threadIdx.x) >> 6);
    int w = __builtin_amdgcn_readfirstlane(w0);
    if (w >= n) return;
    int lane = threadIdx.x & 63;

    float di = dinv[w];
    float acc = bf16_one(hq[(size_t)w * 64 + lane]) * di * di;

    int j0 = start[w];
    int deg = cnt[w];
    for (int base = 0; base < deg; base += 64) {
        int m = min(64, deg - base);
        int2 r = make_int2(0, 0);
        if (lane < m) r = rec[j0 + base + lane];
        int t = 0;
        for (; t + 8 <= m; t += 8) {
            int s[8];
            float wf[8];
            float v[8];
#pragma unroll
            for (int u = 0; u < 8; u++) {
                s[u] = __shfl(r.x, t + u);
                wf[u] = __int_as_float(__shfl(r.y, t + u));
            }
#pragma unroll
            for (int u = 0; u < 8; u++) v[u] = bf16_one(hq[(size_t)s[u] * 64 + lane]);
#pragma unroll
            for (int u = 0; u < 8; u++) acc += v[u] * wf[u];
        }
        for (; t + 4 <= m; t += 4) {
            int s0 = __shfl(r.x, t + 0), s1 = __shfl(r.x, t + 1);
            int s2 = __shfl(r.x, t + 2), s3 = __shfl(r.x, t + 3);
            float w0f = __int_as_float(__shfl(r.y, t + 0));
            float w1f = __int_as_float(__shfl(r.y, t + 1));
            float w2f = __int_as_float(__shfl(r.y, t + 2));
            float w3f = __int_as_float(__shfl(r.y, t + 3));
            float v0 = bf16_one(hq[(size_t)s0 * 64 + lane]);
            float v1 = bf16_one(hq[(size_t)s1 * 64 + lane]);
            float v2 = bf16_one(hq[(size_t)s2 * 64 + lane]);
            float v3 = bf16_one(hq[(size_t)s3 * 64 + lane]);
            acc += v0 * w0f + v1 * w1f + v2 * w2f + v3 * w3f;
        }
        for (; t < m; t++) {
            int s = __shfl(r.x, t);
            float nw = __int_as_float(__shfl(r.y, t));
            acc += bf16_one(hq[(size_t)s * 64 + lane]) * nw;
        }
    }

    acc += bias[lane];
    out[(size_t)w * 64 + lane] = acc;
}

extern "C" void kernel_launch(void* const* d_in, const int* in_sizes, int n_in,
                              void* d_out, int out_size, void* d_ws, size_t ws_size,
                              hipStream_t stream) {
    const float* x = (const float*)d_in[0];
    const int* edge = (const int*)d_in[1];
    const float* W1 = (const float*)d_in[2];
    const float* b1 = (const float*)d_in[3];
    const float* W2 = (const float*)d_in[4];
    const float* b2 = (const float*)d_in[5];

    const int N = in_sizes[0] / 128;
    const int E = in_sizes[1] / 2;
    const int* src = edge;
    const int* dst = edge + E;
    const int NB = (N + (1 << BSH) - 1) >> BSH;   // coarse buckets (<= 256)

    // workspace carve-up (all chunks 16B-aligned for these sizes)
    char* p = (char*)d_ws;
    int* cnt = (int*)p;       p += (size_t)N * 4;
    int* startA = (int*)p;    p += (size_t)N * 4;
    int* bcnt = (int*)p;      p += NBMAX * 4;
    int* bstart = (int*)p;    p += NBMAX * 4;
    int* bcursor = (int*)p;   p += NBMAX * 4;
    float* dinv = (float*)p;  p += (size_t)N * 4;
    int2* rec = (int2*)p;     p += (size_t)E * 8;       // (src, norm) per edge
    uint* hq = (uint*)p;      p += (size_t)N * 64 * 4;  // h = x@W1, bf16 pairs
    uint* g = (uint*)p;       p += (size_t)N * 64 * 4;  // relu(agg) bf16 pairs
    ushort* h2q = (ushort*)p; p += (size_t)N * 64 * 2;  // h2 = g@W2, bf16

    // staged (src,dst) records alias g: dead before aggregate128q writes g
    int2* staged = (int2*)g;

    float* out = (float*)d_out;
    const int eblocks = (E + 2047) / 2048;

    // CSR build (two-level bucketed, zero per-node global atomics)
    (void)hipMemsetAsync(bcnt, 0, NBMAX * 4, stream);
    bucket_hist_kernel<<<eblocks, 256, 0, stream>>>(dst, bcnt, E, NB);
    bucket_scan<<<1, NBMAX, 0, stream>>>(bcnt, bstart, bcursor, NB);
    partition_kernel<<<eblocks, 256, 0, stream>>>(src, dst, bcursor, staged, E, NB);
    fine_count_kernel<<<NB, 256, 0, stream>>>(staged, bstart, bcnt, cnt, startA, dinv, N);
    fine_fill_kernel<<<NB, 256, 0, stream>>>(staged, bstart, bcnt, startA, dinv, rec, N);

    const int gblocks = (N + 63) / 64;

    // layer 1: h = x @ W1 (bf16); g = relu(Anorm @ h + b1) (bf16)
    gemm_mfma<128, true><<<gblocks, 256, 0, stream>>>(x, W1, hq, N);
    aggregate128q<<<(N + 3) / 4, 256, 0, stream>>>(hq, rec, startA, cnt, dinv, b1, g, N);

    // layer 2: h2 = g @ W2 (bf16); out = Anorm @ h2 + b2
    gemm_mfma<64, false><<<gblocks, 256, 0, stream>>>(g, W2, (uint*)h2q, N);
    aggregate64q<<<(N + 3) / 4, 256, 0, stream>>>(h2q, rec, startA, cnt, dinv, b2, out, N);
}

// Round 7
// 323.589 us; speedup vs baseline: 2.2074x; 1.0196x over previous
//
#include <hip/hip_runtime.h>
#include <hip/hip_bf16.h>

// GCN 2-layer: h = relu(Anorm @ (x@W1) + b1); out = Anorm @ (h@W2) + b2
// R7 changes vs R6:
//  - aggregations: half-wave split (2 edges per load instr, 8B/lane),
//    wave-uniform record loads (no shfl broadcast), shfl_xor(32) combine
//  - bucket_hist / partition: int4-vectorized edge reads

#define NTHREADS 256
#define BSH 9                 // bucket = dst >> 9 (512 nodes/bucket)
#define NBMAX 256

typedef unsigned int uint;
typedef unsigned short ushort;
typedef __attribute__((ext_vector_type(8))) short short8;
typedef __attribute__((ext_vector_type(4))) float floatx4;

__device__ __forceinline__ uint pack_bf16(float a, float b) {
    __hip_bfloat162 h = __float22bfloat162_rn(make_float2(a, b));
    return *reinterpret_cast<uint*>(&h);
}
__device__ __forceinline__ float bf16_lo(uint q) { return __uint_as_float(q << 16); }
__device__ __forceinline__ float bf16_hi(uint q) { return __uint_as_float(q & 0xffff0000u); }

// ---------- coarse bucket histogram only (no per-node atomics) ----------
__global__ __launch_bounds__(256) void bucket_hist_kernel(
    const int* __restrict__ dst, int* __restrict__ bcnt, int e, int nb) {
    __shared__ int hist[NBMAX];
    int t = threadIdx.x;
    for (int b = t; b < nb; b += 256) hist[b] = 0;
    __syncthreads();
    int e0 = blockIdx.x * 2048;
#pragma unroll
    for (int v = 0; v < 2; v++) {
        int gi = e0 + t * 8 + v * 4;
        if (gi + 3 < e) {
            int4 d4 = *(const int4*)&dst[gi];
            atomicAdd(&hist[d4.x >> BSH], 1);
            atomicAdd(&hist[d4.y >> BSH], 1);
            atomicAdd(&hist[d4.z >> BSH], 1);
            atomicAdd(&hist[d4.w >> BSH], 1);
        } else {
            for (int j = 0; j < 4; j++)
                if (gi + j < e) atomicAdd(&hist[dst[gi + j] >> BSH], 1);
        }
    }
    __syncthreads();
    for (int b = t; b < nb; b += 256) {
        int v = hist[b];
        if (v) atomicAdd(&bcnt[b], v);
    }
}

// ---------- bucket scan (nb <= 256, single block) ----------
__global__ void bucket_scan(const int* __restrict__ bcnt, int* __restrict__ bstart,
                            int* __restrict__ bcursor, int nb) {
    __shared__ int buf[NBMAX];
    int t = threadIdx.x;
    int v = (t < nb) ? bcnt[t] : 0;
    buf[t] = v;
    __syncthreads();
    int x = v;
    for (int off = 1; off < NBMAX; off <<= 1) {
        int y = (t >= off) ? buf[t - off] : 0;
        __syncthreads();
        x += y;
        buf[t] = x;
        __syncthreads();
    }
    if (t < nb) {
        bstart[t] = x - v;
        bcursor[t] = x - v;
    }
}

// ---------- coarse partition: staged[] = (src,dst) grouped by bucket ----------
__global__ __launch_bounds__(256) void partition_kernel(
    const int* __restrict__ src, const int* __restrict__ dst,
    int* __restrict__ bcursor, int2* __restrict__ staged, int e, int nb) {
    __shared__ int eS[2048];
    __shared__ int eD[2048];
    __shared__ int hist[NBMAX];
    __shared__ int base[NBMAX];
    int t = threadIdx.x;
    int e0 = blockIdx.x * 2048;

    for (int b = t; b < nb; b += 256) hist[b] = 0;
    __syncthreads();
#pragma unroll
    for (int v = 0; v < 2; v++) {
        int li = t * 8 + v * 4;
        int gi = e0 + li;
        int4 s4, d4;
        if (gi + 3 < e) {
            s4 = *(const int4*)&src[gi];
            d4 = *(const int4*)&dst[gi];
        } else {
            const int* sp = &src[gi];
            const int* dp = &dst[gi];
            s4.x = (gi + 0 < e) ? sp[0] : 0;  d4.x = (gi + 0 < e) ? dp[0] : -1;
            s4.y = (gi + 1 < e) ? sp[1] : 0;  d4.y = (gi + 1 < e) ? dp[1] : -1;
            s4.z = (gi + 2 < e) ? sp[2] : 0;  d4.z = (gi + 2 < e) ? dp[2] : -1;
            s4.w = (gi + 3 < e) ? sp[3] : 0;  d4.w = (gi + 3 < e) ? dp[3] : -1;
        }
        *(int4*)&eS[li] = s4;
        *(int4*)&eD[li] = d4;
        if (d4.x >= 0) atomicAdd(&hist[d4.x >> BSH], 1);
        if (d4.y >= 0) atomicAdd(&hist[d4.y >> BSH], 1);
        if (d4.z >= 0) atomicAdd(&hist[d4.z >> BSH], 1);
        if (d4.w >= 0) atomicAdd(&hist[d4.w >> BSH], 1);
    }
    __syncthreads();
    for (int b = t; b < nb; b += 256) {
        int v = hist[b];
        base[b] = v ? atomicAdd(&bcursor[b], v) : 0;
        hist[b] = 0;   // reset for rank pass
    }
    __syncthreads();
#pragma unroll
    for (int i = 0; i < 8; i++) {
        int li = t + i * 256;
        int d = eD[li];
        if (d >= 0) {
            int b = d >> BSH;
            int r = atomicAdd(&hist[b], 1);
            staged[base[b] + r] = make_int2(eS[li], d);
        }
    }
}

// ---------- per-bucket: LDS degree count + scan -> cnt/startA/dinv ----------
__global__ __launch_bounds__(256) void fine_count_kernel(
    const int2* __restrict__ staged, const int* __restrict__ bstart,
    const int* __restrict__ bcnt, int* __restrict__ cnt,
    int* __restrict__ startA, float* __restrict__ dinv, int n) {
    __shared__ int lcnt[512];
    __shared__ int tsum[256];
    int b = blockIdx.x;
    int t = threadIdx.x;
    lcnt[t] = 0;
    lcnt[t + 256] = 0;
    __syncthreads();
    int s0 = bstart[b];
    int m = bcnt[b];
    for (int i = t; i < m; i += 256)
        atomicAdd(&lcnt[staged[s0 + i].y & 511], 1);
    __syncthreads();
    int v0 = lcnt[2 * t];
    int v1 = lcnt[2 * t + 1];
    int tot = v0 + v1;
    tsum[t] = tot;
    __syncthreads();
    int x = tot;
    for (int off = 1; off < 256; off <<= 1) {
        int y = (t >= off) ? tsum[t - off] : 0;
        __syncthreads();
        x += y;
        tsum[t] = x;
        __syncthreads();
    }
    int excl = x - tot;
    int node = (b << BSH) + 2 * t;
    if (node < n) {
        cnt[node] = v0;
        startA[node] = s0 + excl;
        dinv[node] = rsqrtf((float)v0 + 1.0f);
    }
    if (node + 1 < n) {
        cnt[node + 1] = v1;
        startA[node + 1] = s0 + excl + v0;
        dinv[node + 1] = rsqrtf((float)v1 + 1.0f);
    }
}

// ---------- per-bucket fill in hot window: rec[] = (src, norm) by dst ----------
__global__ __launch_bounds__(256) void fine_fill_kernel(
    const int2* __restrict__ staged, const int* __restrict__ bstart,
    const int* __restrict__ bcnt, const int* __restrict__ startA,
    const float* __restrict__ dinv, int2* __restrict__ rec, int n) {
    __shared__ int lcur[512];
    __shared__ float ldv[512];
    int b = blockIdx.x;
    int t = threadIdx.x;
    int nb0 = b << BSH;
    for (int i = t; i < 512; i += 256) {
        int node = nb0 + i;
        lcur[i] = (node < n) ? startA[node] : 0;
        ldv[i] = (node < n) ? dinv[node] : 0.f;
    }
    __syncthreads();
    int s0 = bstart[b];
    int m = bcnt[b];
    for (int i = t; i < m; i += 256) {
        int2 ed = staged[s0 + i];
        int li = ed.y & 511;
        int pos = atomicAdd(&lcur[li], 1);
        float nw = dinv[ed.x] * ldv[li];
        rec[pos] = make_int2(ed.x, __float_as_int(nw));
    }
}

// ---------- bf16 MFMA GEMM: Cq[n,COLS](bf16) = X[n,128] @ W[128,COLS] ----------
template <int COLS, bool XF32>
__global__ __launch_bounds__(256) void gemm_mfma(const void* __restrict__ Xv,
                                                 const float* __restrict__ W,
                                                 uint* __restrict__ Cq, int n) {
    __shared__ ushort sX[64 * 128];
    __shared__ ushort sWT[COLS * 128];
    int t = threadIdx.x;
    int rbase = blockIdx.x * 64;

    if (XF32) {
        const float* X = (const float*)Xv;
#pragma unroll
        for (int i = 0; i < 8; i++) {
            int f = t + 256 * i;
            int r = f >> 5;
            int c4 = f & 31;
            float4 v = make_float4(0.f, 0.f, 0.f, 0.f);
            int gr = rbase + r;
            if (gr < n) v = *(const float4*)(X + (size_t)gr * 128 + c4 * 4);
            uint lo = pack_bf16(v.x, v.y);
            uint hi = pack_bf16(v.z, v.w);
            int chunk = c4 >> 1;
            int sub = (c4 & 1) * 4;
            int off = r * 128 + (((chunk ^ (r & 15)) << 3) + sub);
            *(uint2*)&sX[off] = make_uint2(lo, hi);
        }
    } else {
        const ushort* X = (const ushort*)Xv;
#pragma unroll
        for (int i = 0; i < 4; i++) {
            int f = t + 256 * i;
            int r = f >> 4;
            int chunk = f & 15;
            uint4 v = make_uint4(0, 0, 0, 0);
            int gr = rbase + r;
            if (gr < n) v = *(const uint4*)(X + (size_t)gr * 128 + chunk * 8);
            int off = r * 128 + ((chunk ^ (r & 15)) << 3);
            *(uint4*)&sX[off] = v;
        }
    }
    {
        constexpr int UNITS = 64 * (COLS / 4);
        constexpr int PER_T = UNITS / 256;
#pragma unroll
        for (int i = 0; i < PER_T; i++) {
            int u = t + 256 * i;
            int kp = u / (COLS / 4);
            int n4 = u % (COLS / 4);
            int k = kp * 2;
            float4 w0 = *(const float4*)(W + (size_t)k * COLS + n4 * 4);
            float4 w1 = *(const float4*)(W + (size_t)(k + 1) * COLS + n4 * 4);
            int chunk = k >> 3;
            int sub = k & 7;
            const float* a0 = (const float*)&w0;
            const float* a1 = (const float*)&w1;
#pragma unroll
            for (int j = 0; j < 4; j++) {
                int nn = n4 * 4 + j;
                uint pk = pack_bf16(a0[j], a1[j]);
                int off = nn * 128 + (((chunk ^ (nn & 15)) << 3) + sub);
                *(uint*)&sWT[off] = pk;
            }
        }
    }
    __syncthreads();

    int lane = t & 63;
    int wave = t >> 6;
    int m = lane & 15;
    int q = lane >> 4;
    int r0 = wave * 16;

    floatx4 acc[COLS / 16];
#pragma unroll
    for (int c = 0; c < COLS / 16; c++) acc[c] = (floatx4){0.f, 0.f, 0.f, 0.f};

#pragma unroll
    for (int ks = 0; ks < 4; ks++) {
        int rr = r0 + m;
        int ca = (ks * 4 + q) ^ (rr & 15);
        short8 afrag = *(const short8*)&sX[rr * 128 + (ca << 3)];
#pragma unroll
        for (int c = 0; c < COLS / 16; c++) {
            int nn = c * 16 + m;
            int cb = (ks * 4 + q) ^ (nn & 15);
            short8 bfrag = *(const short8*)&sWT[nn * 128 + (cb << 3)];
            acc[c] = __builtin_amdgcn_mfma_f32_16x16x32_bf16(bfrag, afrag, acc[c], 0, 0, 0);
        }
    }

    int gr = rbase + r0 + m;
    if (gr < n) {
#pragma unroll
        for (int c = 0; c < COLS / 16; c++) {
            uint2 pk;
            pk.x = pack_bf16(acc[c][0], acc[c][1]);
            pk.y = pack_bf16(acc[c][2], acc[c][3]);
            *(uint2*)&Cq[(size_t)gr * (COLS / 2) + c * 8 + q * 2] = pk;
        }
    }
}

// ---------- pull aggregation, D=128 (bf16 in, bf16 out + relu) ----------
// one wave/node, half-wave split: lanes 0-31 even edges, 32-63 odd edges,
// 8B/lane row slices; records via wave-uniform loads (no shfl broadcast).
__global__ __launch_bounds__(256) void aggregate128q(
    const uint* __restrict__ hq, const int2* __restrict__ rec,
    const int* __restrict__ start, const int* __restrict__ cnt,
    const float* __restrict__ dinv, const float* __restrict__ bias,
    uint* __restrict__ outq, int n) {
    int w = (int)((blockIdx.x * blockDim.x + threadIdx.x) >> 6);
    if (w >= n) return;
    int lane = threadIdx.x & 63;
    int half = lane >> 5;
    int fl = lane & 31;
    const uint2* h2 = (const uint2*)hq;   // row = 32 uint2 (256B)

    float a0 = 0.f, a1 = 0.f, a2 = 0.f, a3 = 0.f;
    float di = dinv[w];
    if (half == 0) {
        uint2 q = h2[(size_t)w * 32 + fl];
        float sw = di * di;
        a0 = bf16_lo(q.x) * sw; a1 = bf16_hi(q.x) * sw;
        a2 = bf16_lo(q.y) * sw; a3 = bf16_hi(q.y) * sw;
    }
    int j0 = __builtin_amdgcn_readfirstlane(start[w]);
    int deg = __builtin_amdgcn_readfirstlane(cnt[w]);
    const int2* rp = rec + j0;

    int t = 0;
    for (; t + 16 <= deg; t += 16) {
        uint2 q[8]; float wf[8];
#pragma unroll
        for (int u = 0; u < 8; u++) {
            int2 ea = rp[t + 2 * u];
            int2 eb = rp[t + 2 * u + 1];
            int s = half ? eb.x : ea.x;
            wf[u] = __int_as_float(half ? eb.y : ea.y);
            q[u] = h2[(size_t)s * 32 + fl];
        }
#pragma unroll
        for (int u = 0; u < 8; u++) {
            a0 += bf16_lo(q[u].x) * wf[u]; a1 += bf16_hi(q[u].x) * wf[u];
            a2 += bf16_lo(q[u].y) * wf[u]; a3 += bf16_hi(q[u].y) * wf[u];
        }
    }
    for (; t + 4 <= deg; t += 4) {
        uint2 q[2]; float wf[2];
#pragma unroll
        for (int u = 0; u < 2; u++) {
            int2 ea = rp[t + 2 * u];
            int2 eb = rp[t + 2 * u + 1];
            int s = half ? eb.x : ea.x;
            wf[u] = __int_as_float(half ? eb.y : ea.y);
            q[u] = h2[(size_t)s * 32 + fl];
        }
#pragma unroll
        for (int u = 0; u < 2; u++) {
            a0 += bf16_lo(q[u].x) * wf[u]; a1 += bf16_hi(q[u].x) * wf[u];
            a2 += bf16_lo(q[u].y) * wf[u]; a3 += bf16_hi(q[u].y) * wf[u];
        }
    }
    for (; t < deg; t += 2) {
        int2 ea = rp[t];
        int2 eb = (t + 1 < deg) ? rp[t + 1] : make_int2(0, 0);
        int s = half ? eb.x : ea.x;
        float wfv = __int_as_float(half ? eb.y : ea.y);
        uint2 q = h2[(size_t)s * 32 + fl];
        a0 += bf16_lo(q.x) * wfv; a1 += bf16_hi(q.x) * wfv;
        a2 += bf16_lo(q.y) * wfv; a3 += bf16_hi(q.y) * wfv;
    }

    a0 += __shfl(a0, lane ^ 32);
    a1 += __shfl(a1, lane ^ 32);
    a2 += __shfl(a2, lane ^ 32);
    a3 += __shfl(a3, lane ^ 32);
    if (half == 0) {
        float4 bb = *(const float4*)&bias[4 * fl];
        float o0 = fmaxf(a0 + bb.x, 0.f);
        float o1 = fmaxf(a1 + bb.y, 0.f);
        float o2 = fmaxf(a2 + bb.z, 0.f);
        float o3 = fmaxf(a3 + bb.w, 0.f);
        uint2 pk;
        pk.x = pack_bf16(o0, o1);
        pk.y = pack_bf16(o2, o3);
        *(uint2*)&outq[(size_t)w * 64 + fl * 2] = pk;
    }
}

// ---------- pull aggregation, D=64 (bf16 in, f32 out), half-wave ----------
__global__ __launch_bounds__(256) void aggregate64q(
    const ushort* __restrict__ hq, const int2* __restrict__ rec,
    const int* __restrict__ start, const int* __restrict__ cnt,
    const float* __restrict__ dinv, const float* __restrict__ bias,
    float* __restrict__ out, int n) {
    int w = (int)((blockIdx.x * blockDim.x + threadIdx.x) >> 6);
    if (w >= n) return;
    int lane = threadIdx.x & 63;
    int half = lane >> 5;
    int fl = lane & 31;
    const uint* h2 = (const uint*)hq;    // row = 32 uints (128B)

    float a0 = 0.f, a1 = 0.f;
    float di = dinv[w];
    if (half == 0) {
        uint q = h2[(size_t)w * 32 + fl];
        float sw = di * di;
        a0 = bf16_lo(q) * sw;
        a1 = bf16_hi(q) * sw;
    }
    int j0 = __builtin_amdgcn_readfirstlane(start[w]);
    int deg = __builtin_amdgcn_readfirstlane(cnt[w]);
    const int2* rp = rec + j0;

    int t = 0;
    for (; t + 16 <= deg; t += 16) {
        uint q[8]; float wf[8];
#pragma unroll
        for (int u = 0; u < 8; u++) {
            int2 ea = rp[t + 2 * u];
            int2 eb = rp[t + 2 * u + 1];
            int s = half ? eb.x : ea.x;
            wf[u] = __int_as_float(half ? eb.y : ea.y);
            q[u] = h2[(size_t)s * 32 + fl];
        }
#pragma unroll
        for (int u = 0; u < 8; u++) {
            a0 += bf16_lo(q[u]) * wf[u];
            a1 += bf16_hi(q[u]) * wf[u];
        }
    }
    for (; t + 4 <= deg; t += 4) {
        uint q[2]; float wf[2];
#pragma unroll
        for (int u = 0; u < 2; u++) {
            int2 ea = rp[t + 2 * u];
            int2 eb = rp[t + 2 * u + 1];
            int s = half ? eb.x : ea.x;
            wf[u] = __int_as_float(half ? eb.y : ea.y);
            q[u] = h2[(size_t)s * 32 + fl];
        }
#pragma unroll
        for (int u = 0; u < 2; u++) {
            a0 += bf16_lo(q[u]) * wf[u];
            a1 += bf16_hi(q[u]) * wf[u];
        }
    }
    for (; t < deg; t += 2) {
        int2 ea = rp[t];
        int2 eb = (t + 1 < deg) ? rp[t + 1] : make_int2(0, 0);
        int s = half ? eb.x : ea.x;
        float wfv = __int_as_float(half ? eb.y : ea.y);
        uint q = h2[(size_t)s * 32 + fl];
        a0 += bf16_lo(q) * wfv;
        a1 += bf16_hi(q) * wfv;
    }

    a0 += __shfl(a0, lane ^ 32);
    a1 += __shfl(a1, lane ^ 32);
    if (half == 0) {
        float2 bb = *(const float2*)&bias[2 * fl];
        float2 o;
        o.x = a0 + bb.x;
        o.y = a1 + bb.y;
        ((float2*)out)[(size_t)w * 32 + fl] = o;
    }
}

extern "C" void kernel_launch(void* const* d_in, const int* in_sizes, int n_in,
                              void* d_out, int out_size, void* d_ws, size_t ws_size,
                              hipStream_t stream) {
    const float* x = (const float*)d_in[0];
    const int* edge = (const int*)d_in[1];
    const float* W1 = (const float*)d_in[2];
    const float* b1 = (const float*)d_in[3];
    const float* W2 = (const float*)d_in[4];
    const float* b2 = (const float*)d_in[5];

    const int N = in_sizes[0] / 128;
    const int E = in_sizes[1] / 2;
    const int* src = edge;
    const int* dst = edge + E;
    const int NB = (N + (1 << BSH) - 1) >> BSH;   // coarse buckets (<= 256)

    // workspace carve-up (all chunks 16B-aligned for these sizes)
    char* p = (char*)d_ws;
    int* cnt = (int*)p;       p += (size_t)N * 4;
    int* startA = (int*)p;    p += (size_t)N * 4;
    int* bcnt = (int*)p;      p += NBMAX * 4;
    int* bstart = (int*)p;    p += NBMAX * 4;
    int* bcursor = (int*)p;   p += NBMAX * 4;
    float* dinv = (float*)p;  p += (size_t)N * 4;
    int2* rec = (int2*)p;     p += (size_t)E * 8;       // (src, norm) per edge
    uint* hq = (uint*)p;      p += (size_t)N * 64 * 4;  // h = x@W1, bf16 pairs
    uint* g = (uint*)p;       p += (size_t)N * 64 * 4;  // relu(agg) bf16 pairs
    ushort* h2q = (ushort*)p; p += (size_t)N * 64 * 2;  // h2 = g@W2, bf16

    // staged (src,dst) records alias g: dead before aggregate128q writes g
    int2* staged = (int2*)g;

    float* out = (float*)d_out;
    const int eblocks = (E + 2047) / 2048;

    // CSR build (two-level bucketed, zero per-node global atomics)
    (void)hipMemsetAsync(bcnt, 0, NBMAX * 4, stream);
    bucket_hist_kernel<<<eblocks, 256, 0, stream>>>(dst, bcnt, E, NB);
    bucket_scan<<<1, NBMAX, 0, stream>>>(bcnt, bstart, bcursor, NB);
    partition_kernel<<<eblocks, 256, 0, stream>>>(src, dst, bcursor, staged, E, NB);
    fine_count_kernel<<<NB, 256, 0, stream>>>(staged, bstart, bcnt, cnt, startA, dinv, N);
    fine_fill_kernel<<<NB, 256, 0, stream>>>(staged, bstart, bcnt, startA, dinv, rec, N);

    const int gblocks = (N + 63) / 64;

    // layer 1: h = x @ W1 (bf16); g = relu(Anorm @ h + b1) (bf16)
    gemm_mfma<128, true><<<gblocks, 256, 0, stream>>>(x, W1, hq, N);
    aggregate128q<<<(N + 3) / 4, 256, 0, stream>>>(hq, rec, startA, cnt, dinv, b1, g, N);

    // layer 2: h2 = g @ W2 (bf16); out = Anorm @ h2 + b2
    gemm_mfma<64, false><<<gblocks, 256, 0, stream>>>(g, W2, (uint*)h2q, N);
    aggregate64q<<<(N + 3) / 4, 256, 0, stream>>>(h2q, rec, startA, cnt, dinv, b2, out, N);
}

// Round 8
// 320.244 us; speedup vs baseline: 2.2304x; 1.0104x over previous
//
#include <hip/hip_runtime.h>
#include <hip/hip_bf16.h>

// GCN 2-layer: h = relu(Anorm @ (x@W1) + b1); out = Anorm @ (h@W2) + b2
// R8 changes vs R7:
//  - aggregations: ONE HALF-WAVE PER NODE (2 nodes/wave) -> 16 row-gathers
//    in flight per wave (was 8); row = 32 lanes x 8B (D=128) / 4B (D=64)
//  - meta int4 = (start, deg, dinv^2, -) built in fine_count: one 16B load
//    replaces 3 dependent prologue loads

#define NTHREADS 256
#define BSH 9                 // bucket = dst >> 9 (512 nodes/bucket)
#define NBMAX 256

typedef unsigned int uint;
typedef unsigned short ushort;
typedef __attribute__((ext_vector_type(8))) short short8;
typedef __attribute__((ext_vector_type(4))) float floatx4;

__device__ __forceinline__ uint pack_bf16(float a, float b) {
    __hip_bfloat162 h = __float22bfloat162_rn(make_float2(a, b));
    return *reinterpret_cast<uint*>(&h);
}
__device__ __forceinline__ float bf16_lo(uint q) { return __uint_as_float(q << 16); }
__device__ __forceinline__ float bf16_hi(uint q) { return __uint_as_float(q & 0xffff0000u); }

// ---------- coarse bucket histogram only (no per-node atomics) ----------
__global__ __launch_bounds__(256) void bucket_hist_kernel(
    const int* __restrict__ dst, int* __restrict__ bcnt, int e, int nb) {
    __shared__ int hist[NBMAX];
    int t = threadIdx.x;
    for (int b = t; b < nb; b += 256) hist[b] = 0;
    __syncthreads();
    int e0 = blockIdx.x * 2048;
#pragma unroll
    for (int v = 0; v < 2; v++) {
        int gi = e0 + t * 8 + v * 4;
        if (gi + 3 < e) {
            int4 d4 = *(const int4*)&dst[gi];
            atomicAdd(&hist[d4.x >> BSH], 1);
            atomicAdd(&hist[d4.y >> BSH], 1);
            atomicAdd(&hist[d4.z >> BSH], 1);
            atomicAdd(&hist[d4.w >> BSH], 1);
        } else {
            for (int j = 0; j < 4; j++)
                if (gi + j < e) atomicAdd(&hist[dst[gi + j] >> BSH], 1);
        }
    }
    __syncthreads();
    for (int b = t; b < nb; b += 256) {
        int v = hist[b];
        if (v) atomicAdd(&bcnt[b], v);
    }
}

// ---------- bucket scan (nb <= 256, single block) ----------
__global__ void bucket_scan(const int* __restrict__ bcnt, int* __restrict__ bstart,
                            int* __restrict__ bcursor, int nb) {
    __shared__ int buf[NBMAX];
    int t = threadIdx.x;
    int v = (t < nb) ? bcnt[t] : 0;
    buf[t] = v;
    __syncthreads();
    int x = v;
    for (int off = 1; off < NBMAX; off <<= 1) {
        int y = (t >= off) ? buf[t - off] : 0;
        __syncthreads();
        x += y;
        buf[t] = x;
        __syncthreads();
    }
    if (t < nb) {
        bstart[t] = x - v;
        bcursor[t] = x - v;
    }
}

// ---------- coarse partition: staged[] = (src,dst) grouped by bucket ----------
__global__ __launch_bounds__(256) void partition_kernel(
    const int* __restrict__ src, const int* __restrict__ dst,
    int* __restrict__ bcursor, int2* __restrict__ staged, int e, int nb) {
    __shared__ int eS[2048];
    __shared__ int eD[2048];
    __shared__ int hist[NBMAX];
    __shared__ int base[NBMAX];
    int t = threadIdx.x;
    int e0 = blockIdx.x * 2048;

    for (int b = t; b < nb; b += 256) hist[b] = 0;
    __syncthreads();
#pragma unroll
    for (int v = 0; v < 2; v++) {
        int li = t * 8 + v * 4;
        int gi = e0 + li;
        int4 s4, d4;
        if (gi + 3 < e) {
            s4 = *(const int4*)&src[gi];
            d4 = *(const int4*)&dst[gi];
        } else {
            const int* sp = &src[gi];
            const int* dp = &dst[gi];
            s4.x = (gi + 0 < e) ? sp[0] : 0;  d4.x = (gi + 0 < e) ? dp[0] : -1;
            s4.y = (gi + 1 < e) ? sp[1] : 0;  d4.y = (gi + 1 < e) ? dp[1] : -1;
            s4.z = (gi + 2 < e) ? sp[2] : 0;  d4.z = (gi + 2 < e) ? dp[2] : -1;
            s4.w = (gi + 3 < e) ? sp[3] : 0;  d4.w = (gi + 3 < e) ? dp[3] : -1;
        }
        *(int4*)&eS[li] = s4;
        *(int4*)&eD[li] = d4;
        if (d4.x >= 0) atomicAdd(&hist[d4.x >> BSH], 1);
        if (d4.y >= 0) atomicAdd(&hist[d4.y >> BSH], 1);
        if (d4.z >= 0) atomicAdd(&hist[d4.z >> BSH], 1);
        if (d4.w >= 0) atomicAdd(&hist[d4.w >> BSH], 1);
    }
    __syncthreads();
    for (int b = t; b < nb; b += 256) {
        int v = hist[b];
        base[b] = v ? atomicAdd(&bcursor[b], v) : 0;
        hist[b] = 0;   // reset for rank pass
    }
    __syncthreads();
#pragma unroll
    for (int i = 0; i < 8; i++) {
        int li = t + i * 256;
        int d = eD[li];
        if (d >= 0) {
            int b = d >> BSH;
            int r = atomicAdd(&hist[b], 1);
            staged[base[b] + r] = make_int2(eS[li], d);
        }
    }
}

// ---------- per-bucket: LDS degree count + scan -> meta/startA/dinv ----------
__global__ __launch_bounds__(256) void fine_count_kernel(
    const int2* __restrict__ staged, const int* __restrict__ bstart,
    const int* __restrict__ bcnt, int4* __restrict__ meta,
    int* __restrict__ startA, float* __restrict__ dinv, int n) {
    __shared__ int lcnt[512];
    __shared__ int tsum[256];
    int b = blockIdx.x;
    int t = threadIdx.x;
    lcnt[t] = 0;
    lcnt[t + 256] = 0;
    __syncthreads();
    int s0 = bstart[b];
    int m = bcnt[b];
    for (int i = t; i < m; i += 256)
        atomicAdd(&lcnt[staged[s0 + i].y & 511], 1);
    __syncthreads();
    int v0 = lcnt[2 * t];
    int v1 = lcnt[2 * t + 1];
    int tot = v0 + v1;
    tsum[t] = tot;
    __syncthreads();
    int x = tot;
    for (int off = 1; off < 256; off <<= 1) {
        int y = (t >= off) ? tsum[t - off] : 0;
        __syncthreads();
        x += y;
        tsum[t] = x;
        __syncthreads();
    }
    int excl = x - tot;
    int node = (b << BSH) + 2 * t;
    if (node < n) {
        float di = rsqrtf((float)v0 + 1.0f);
        startA[node] = s0 + excl;
        dinv[node] = di;
        meta[node] = make_int4(s0 + excl, v0, __float_as_int(di * di), 0);
    }
    if (node + 1 < n) {
        float di = rsqrtf((float)v1 + 1.0f);
        startA[node + 1] = s0 + excl + v0;
        dinv[node + 1] = di;
        meta[node + 1] = make_int4(s0 + excl + v0, v1, __float_as_int(di * di), 0);
    }
}

// ---------- per-bucket fill in hot window: rec[] = (src, norm) by dst ----------
__global__ __launch_bounds__(256) void fine_fill_kernel(
    const int2* __restrict__ staged, const int* __restrict__ bstart,
    const int* __restrict__ bcnt, const int* __restrict__ startA,
    const float* __restrict__ dinv, int2* __restrict__ rec, int n) {
    __shared__ int lcur[512];
    __shared__ float ldv[512];
    int b = blockIdx.x;
    int t = threadIdx.x;
    int nb0 = b << BSH;
    for (int i = t; i < 512; i += 256) {
        int node = nb0 + i;
        lcur[i] = (node < n) ? startA[node] : 0;
        ldv[i] = (node < n) ? dinv[node] : 0.f;
    }
    __syncthreads();
    int s0 = bstart[b];
    int m = bcnt[b];
    for (int i = t; i < m; i += 256) {
        int2 ed = staged[s0 + i];
        int li = ed.y & 511;
        int pos = atomicAdd(&lcur[li], 1);
        float nw = dinv[ed.x] * ldv[li];
        rec[pos] = make_int2(ed.x, __float_as_int(nw));
    }
}

// ---------- bf16 MFMA GEMM: Cq[n,COLS](bf16) = X[n,128] @ W[128,COLS] ----------
template <int COLS, bool XF32>
__global__ __launch_bounds__(256) void gemm_mfma(const void* __restrict__ Xv,
                                                 const float* __restrict__ W,
                                                 uint* __restrict__ Cq, int n) {
    __shared__ ushort sX[64 * 128];
    __shared__ ushort sWT[COLS * 128];
    int t = threadIdx.x;
    int rbase = blockIdx.x * 64;

    if (XF32) {
        const float* X = (const float*)Xv;
#pragma unroll
        for (int i = 0; i < 8; i++) {
            int f = t + 256 * i;
            int r = f >> 5;
            int c4 = f & 31;
            float4 v = make_float4(0.f, 0.f, 0.f, 0.f);
            int gr = rbase + r;
            if (gr < n) v = *(const float4*)(X + (size_t)gr * 128 + c4 * 4);
            uint lo = pack_bf16(v.x, v.y);
            uint hi = pack_bf16(v.z, v.w);
            int chunk = c4 >> 1;
            int sub = (c4 & 1) * 4;
            int off = r * 128 + (((chunk ^ (r & 15)) << 3) + sub);
            *(uint2*)&sX[off] = make_uint2(lo, hi);
        }
    } else {
        const ushort* X = (const ushort*)Xv;
#pragma unroll
        for (int i = 0; i < 4; i++) {
            int f = t + 256 * i;
            int r = f >> 4;
            int chunk = f & 15;
            uint4 v = make_uint4(0, 0, 0, 0);
            int gr = rbase + r;
            if (gr < n) v = *(const uint4*)(X + (size_t)gr * 128 + chunk * 8);
            int off = r * 128 + ((chunk ^ (r & 15)) << 3);
            *(uint4*)&sX[off] = v;
        }
    }
    {
        constexpr int UNITS = 64 * (COLS / 4);
        constexpr int PER_T = UNITS / 256;
#pragma unroll
        for (int i = 0; i < PER_T; i++) {
            int u = t + 256 * i;
            int kp = u / (COLS / 4);
            int n4 = u % (COLS / 4);
            int k = kp * 2;
            float4 w0 = *(const float4*)(W + (size_t)k * COLS + n4 * 4);
            float4 w1 = *(const float4*)(W + (size_t)(k + 1) * COLS + n4 * 4);
            int chunk = k >> 3;
            int sub = k & 7;
            const float* a0 = (const float*)&w0;
            const float* a1 = (const float*)&w1;
#pragma unroll
            for (int j = 0; j < 4; j++) {
                int nn = n4 * 4 + j;
                uint pk = pack_bf16(a0[j], a1[j]);
                int off = nn * 128 + (((chunk ^ (nn & 15)) << 3) + sub);
                *(uint*)&sWT[off] = pk;
            }
        }
    }
    __syncthreads();

    int lane = t & 63;
    int wave = t >> 6;
    int m = lane & 15;
    int q = lane >> 4;
    int r0 = wave * 16;

    floatx4 acc[COLS / 16];
#pragma unroll
    for (int c = 0; c < COLS / 16; c++) acc[c] = (floatx4){0.f, 0.f, 0.f, 0.f};

#pragma unroll
    for (int ks = 0; ks < 4; ks++) {
        int rr = r0 + m;
        int ca = (ks * 4 + q) ^ (rr & 15);
        short8 afrag = *(const short8*)&sX[rr * 128 + (ca << 3)];
#pragma unroll
        for (int c = 0; c < COLS / 16; c++) {
            int nn = c * 16 + m;
            int cb = (ks * 4 + q) ^ (nn & 15);
            short8 bfrag = *(const short8*)&sWT[nn * 128 + (cb << 3)];
            acc[c] = __builtin_amdgcn_mfma_f32_16x16x32_bf16(bfrag, afrag, acc[c], 0, 0, 0);
        }
    }

    int gr = rbase + r0 + m;
    if (gr < n) {
#pragma unroll
        for (int c = 0; c < COLS / 16; c++) {
            uint2 pk;
            pk.x = pack_bf16(acc[c][0], acc[c][1]);
            pk.y = pack_bf16(acc[c][2], acc[c][3]);
            *(uint2*)&Cq[(size_t)gr * (COLS / 2) + c * 8 + q * 2] = pk;
        }
    }
}

// ---------- pull aggregation, D=128 (bf16 in, bf16 out + relu) ----------
// ONE HALF-WAVE (32 lanes) PER NODE: row = 32 x uint2 (256B).
// 8 row-gathers in flight per node -> 16 per wave.
__global__ __launch_bounds__(256) void aggregate128q(
    const uint* __restrict__ hq, const int2* __restrict__ rec,
    const int4* __restrict__ meta, const float* __restrict__ bias,
    uint* __restrict__ outq, int n) {
    int w = (int)((blockIdx.x * blockDim.x + threadIdx.x) >> 5);
    if (w >= n) return;
    int fl = threadIdx.x & 31;
    const uint2* h2 = (const uint2*)hq;   // row = 32 uint2 (256B)

    int4 mt = meta[w];
    int j0 = mt.x;
    int deg = mt.y;
    float swq = __int_as_float(mt.z);     // dinv^2 (self-loop weight)

    uint2 qs = h2[(size_t)w * 32 + fl];
    float a0 = bf16_lo(qs.x) * swq, a1 = bf16_hi(qs.x) * swq;
    float a2 = bf16_lo(qs.y) * swq, a3 = bf16_hi(qs.y) * swq;

    const int2* rp = rec + j0;
    int t = 0;
    for (; t + 8 <= deg; t += 8) {
        uint2 q[8]; float wf[8];
#pragma unroll
        for (int u = 0; u < 8; u++) {
            int2 e = rp[t + u];
            wf[u] = __int_as_float(e.y);
            q[u] = h2[(size_t)e.x * 32 + fl];
        }
#pragma unroll
        for (int u = 0; u < 8; u++) {
            a0 += bf16_lo(q[u].x) * wf[u]; a1 += bf16_hi(q[u].x) * wf[u];
            a2 += bf16_lo(q[u].y) * wf[u]; a3 += bf16_hi(q[u].y) * wf[u];
        }
    }
    for (; t + 2 <= deg; t += 2) {
        int2 e0 = rp[t], e1 = rp[t + 1];
        float w0 = __int_as_float(e0.y), w1 = __int_as_float(e1.y);
        uint2 q0 = h2[(size_t)e0.x * 32 + fl];
        uint2 q1 = h2[(size_t)e1.x * 32 + fl];
        a0 += bf16_lo(q0.x) * w0 + bf16_lo(q1.x) * w1;
        a1 += bf16_hi(q0.x) * w0 + bf16_hi(q1.x) * w1;
        a2 += bf16_lo(q0.y) * w0 + bf16_lo(q1.y) * w1;
        a3 += bf16_hi(q0.y) * w0 + bf16_hi(q1.y) * w1;
    }
    if (t < deg) {
        int2 e = rp[t];
        float wv = __int_as_float(e.y);
        uint2 q = h2[(size_t)e.x * 32 + fl];
        a0 += bf16_lo(q.x) * wv; a1 += bf16_hi(q.x) * wv;
        a2 += bf16_lo(q.y) * wv; a3 += bf16_hi(q.y) * wv;
    }

    float4 bb = *(const float4*)&bias[4 * fl];
    float o0 = fmaxf(a0 + bb.x, 0.f);
    float o1 = fmaxf(a1 + bb.y, 0.f);
    float o2 = fmaxf(a2 + bb.z, 0.f);
    float o3 = fmaxf(a3 + bb.w, 0.f);
    uint2 pk;
    pk.x = pack_bf16(o0, o1);
    pk.y = pack_bf16(o2, o3);
    *(uint2*)&outq[(size_t)w * 64 + fl * 2] = pk;
}

// ---------- pull aggregation, D=64 (bf16 in, f32 out), half-wave/node ----------
__global__ __launch_bounds__(256) void aggregate64q(
    const ushort* __restrict__ hq, const int2* __restrict__ rec,
    const int4* __restrict__ meta, const float* __restrict__ bias,
    float* __restrict__ out, int n) {
    int w = (int)((blockIdx.x * blockDim.x + threadIdx.x) >> 5);
    if (w >= n) return;
    int fl = threadIdx.x & 31;
    const uint* h2 = (const uint*)hq;     // row = 32 uints (128B)

    int4 mt = meta[w];
    int j0 = mt.x;
    int deg = mt.y;
    float swq = __int_as_float(mt.z);

    uint qs = h2[(size_t)w * 32 + fl];
    float a0 = bf16_lo(qs) * swq;
    float a1 = bf16_hi(qs) * swq;

    const int2* rp = rec + j0;
    int t = 0;
    for (; t + 8 <= deg; t += 8) {
        uint q[8]; float wf[8];
#pragma unroll
        for (int u = 0; u < 8; u++) {
            int2 e = rp[t + u];
            wf[u] = __int_as_float(e.y);
            q[u] = h2[(size_t)e.x * 32 + fl];
        }
#pragma unroll
        for (int u = 0; u < 8; u++) {
            a0 += bf16_lo(q[u]) * wf[u];
            a1 += bf16_hi(q[u]) * wf[u];
        }
    }
    for (; t + 2 <= deg; t += 2) {
        int2 e0 = rp[t], e1 = rp[t + 1];
        float w0 = __int_as_float(e0.y), w1 = __int_as_float(e1.y);
        uint q0 = h2[(size_t)e0.x * 32 + fl];
        uint q1 = h2[(size_t)e1.x * 32 + fl];
        a0 += bf16_lo(q0) * w0 + bf16_lo(q1) * w1;
        a1 += bf16_hi(q0) * w0 + bf16_hi(q1) * w1;
    }
    if (t < deg) {
        int2 e = rp[t];
        float wv = __int_as_float(e.y);
        uint q = h2[(size_t)e.x * 32 + fl];
        a0 += bf16_lo(q) * wv;
        a1 += bf16_hi(q) * wv;
    }

    float2 bb = *(const float2*)&bias[2 * fl];
    float2 o;
    o.x = a0 + bb.x;
    o.y = a1 + bb.y;
    ((float2*)out)[(size_t)w * 32 + fl] = o;
}

extern "C" void kernel_launch(void* const* d_in, const int* in_sizes, int n_in,
                              void* d_out, int out_size, void* d_ws, size_t ws_size,
                              hipStream_t stream) {
    const float* x = (const float*)d_in[0];
    const int* edge = (const int*)d_in[1];
    const float* W1 = (const float*)d_in[2];
    const float* b1 = (const float*)d_in[3];
    const float* W2 = (const float*)d_in[4];
    const float* b2 = (const float*)d_in[5];

    const int N = in_sizes[0] / 128;
    const int E = in_sizes[1] / 2;
    const int* src = edge;
    const int* dst = edge + E;
    const int NB = (N + (1 << BSH) - 1) >> BSH;   // coarse buckets (<= 256)

    // workspace carve-up (all chunks 16B-aligned for these sizes)
    char* p = (char*)d_ws;
    int* startA = (int*)p;    p += (size_t)N * 4;
    int* bcnt = (int*)p;      p += NBMAX * 4;
    int* bstart = (int*)p;    p += NBMAX * 4;
    int* bcursor = (int*)p;   p += NBMAX * 4;
    float* dinv = (float*)p;  p += (size_t)N * 4;
    int4* meta = (int4*)p;    p += (size_t)N * 16;      // (start, deg, dinv^2, -)
    int2* rec = (int2*)p;     p += (size_t)E * 8;       // (src, norm) per edge
    uint* hq = (uint*)p;      p += (size_t)N * 64 * 4;  // h = x@W1, bf16 pairs
    uint* g = (uint*)p;       p += (size_t)N * 64 * 4;  // relu(agg) bf16 pairs
    ushort* h2q = (ushort*)p; p += (size_t)N * 64 * 2;  // h2 = g@W2, bf16

    // staged (src,dst) records alias g: dead before aggregate128q writes g
    int2* staged = (int2*)g;

    float* out = (float*)d_out;
    const int eblocks = (E + 2047) / 2048;

    // CSR build (two-level bucketed, zero per-node global atomics)
    (void)hipMemsetAsync(bcnt, 0, NBMAX * 4, stream);
    bucket_hist_kernel<<<eblocks, 256, 0, stream>>>(dst, bcnt, E, NB);
    bucket_scan<<<1, NBMAX, 0, stream>>>(bcnt, bstart, bcursor, NB);
    partition_kernel<<<eblocks, 256, 0, stream>>>(src, dst, bcursor, staged, E, NB);
    fine_count_kernel<<<NB, 256, 0, stream>>>(staged, bstart, bcnt, meta, startA, dinv, N);
    fine_fill_kernel<<<NB, 256, 0, stream>>>(staged, bstart, bcnt, startA, dinv, rec, N);

    const int gblocks = (N + 63) / 64;
    const int ablocks = (N + 7) / 8;   // 8 nodes per 256-thread block

    // layer 1: h = x @ W1 (bf16); g = relu(Anorm @ h + b1) (bf16)
    gemm_mfma<128, true><<<gblocks, 256, 0, stream>>>(x, W1, hq, N);
    aggregate128q<<<ablocks, 256, 0, stream>>>(hq, rec, meta, b1, g, N);

    // layer 2: h2 = g @ W2 (bf16); out = Anorm @ h2 + b2
    gemm_mfma<64, false><<<gblocks, 256, 0, stream>>>(g, W2, (uint*)h2q, N);
    aggregate64q<<<ablocks, 256, 0, stream>>>(h2q, rec, meta, b2, out, N);
}

// Round 9
// 298.653 us; speedup vs baseline: 2.3917x; 1.0723x over previous
//
#include <hip/hip_runtime.h>
#include <hip/hip_bf16.h>

// GCN 2-layer: h = relu(Anorm @ (x@W1) + b1); out = Anorm @ (h@W2) + b2
// R9 changes vs R8:
//  - agg128 fused with GEMM2: g tile -> LDS, MFMA 16x16x32 epilogue writes
//    h2 directly (g buffer + gemm64 dispatch eliminated)
//  - rec = src only (4B); norm = dinv[src]*dinv[dst] computed in aggs
//    (dinv 400KB is L2-resident) -> fine_count+fine_fill fused (1 kernel)
//  - meta = (start, deg, dinv, dinv^2)

#define NTHREADS 256
#define BSH 9                 // bucket = dst >> 9 (512 nodes/bucket)
#define NBMAX 256

typedef unsigned int uint;
typedef unsigned short ushort;
typedef __attribute__((ext_vector_type(8))) short short8;
typedef __attribute__((ext_vector_type(4))) float floatx4;

__device__ __forceinline__ uint pack_bf16(float a, float b) {
    __hip_bfloat162 h = __float22bfloat162_rn(make_float2(a, b));
    return *reinterpret_cast<uint*>(&h);
}
__device__ __forceinline__ float bf16_lo(uint q) { return __uint_as_float(q << 16); }
__device__ __forceinline__ float bf16_hi(uint q) { return __uint_as_float(q & 0xffff0000u); }

// ---------- coarse bucket histogram only (no per-node atomics) ----------
__global__ __launch_bounds__(256) void bucket_hist_kernel(
    const int* __restrict__ dst, int* __restrict__ bcnt, int e, int nb) {
    __shared__ int hist[NBMAX];
    int t = threadIdx.x;
    for (int b = t; b < nb; b += 256) hist[b] = 0;
    __syncthreads();
    int e0 = blockIdx.x * 2048;
#pragma unroll
    for (int v = 0; v < 2; v++) {
        int gi = e0 + t * 8 + v * 4;
        if (gi + 3 < e) {
            int4 d4 = *(const int4*)&dst[gi];
            atomicAdd(&hist[d4.x >> BSH], 1);
            atomicAdd(&hist[d4.y >> BSH], 1);
            atomicAdd(&hist[d4.z >> BSH], 1);
            atomicAdd(&hist[d4.w >> BSH], 1);
        } else {
            for (int j = 0; j < 4; j++)
                if (gi + j < e) atomicAdd(&hist[dst[gi + j] >> BSH], 1);
        }
    }
    __syncthreads();
    for (int b = t; b < nb; b += 256) {
        int v = hist[b];
        if (v) atomicAdd(&bcnt[b], v);
    }
}

// ---------- bucket scan (nb <= 256, single block) ----------
__global__ void bucket_scan(const int* __restrict__ bcnt, int* __restrict__ bstart,
                            int* __restrict__ bcursor, int nb) {
    __shared__ int buf[NBMAX];
    int t = threadIdx.x;
    int v = (t < nb) ? bcnt[t] : 0;
    buf[t] = v;
    __syncthreads();
    int x = v;
    for (int off = 1; off < NBMAX; off <<= 1) {
        int y = (t >= off) ? buf[t - off] : 0;
        __syncthreads();
        x += y;
        buf[t] = x;
        __syncthreads();
    }
    if (t < nb) {
        bstart[t] = x - v;
        bcursor[t] = x - v;
    }
}

// ---------- coarse partition: staged[] = (src,dst) grouped by bucket ----------
__global__ __launch_bounds__(256) void partition_kernel(
    const int* __restrict__ src, const int* __restrict__ dst,
    int* __restrict__ bcursor, int2* __restrict__ staged, int e, int nb) {
    __shared__ int eS[2048];
    __shared__ int eD[2048];
    __shared__ int hist[NBMAX];
    __shared__ int base[NBMAX];
    int t = threadIdx.x;
    int e0 = blockIdx.x * 2048;

    for (int b = t; b < nb; b += 256) hist[b] = 0;
    __syncthreads();
#pragma unroll
    for (int v = 0; v < 2; v++) {
        int li = t * 8 + v * 4;
        int gi = e0 + li;
        int4 s4, d4;
        if (gi + 3 < e) {
            s4 = *(const int4*)&src[gi];
            d4 = *(const int4*)&dst[gi];
        } else {
            const int* sp = &src[gi];
            const int* dp = &dst[gi];
            s4.x = (gi + 0 < e) ? sp[0] : 0;  d4.x = (gi + 0 < e) ? dp[0] : -1;
            s4.y = (gi + 1 < e) ? sp[1] : 0;  d4.y = (gi + 1 < e) ? dp[1] : -1;
            s4.z = (gi + 2 < e) ? sp[2] : 0;  d4.z = (gi + 2 < e) ? dp[2] : -1;
            s4.w = (gi + 3 < e) ? sp[3] : 0;  d4.w = (gi + 3 < e) ? dp[3] : -1;
        }
        *(int4*)&eS[li] = s4;
        *(int4*)&eD[li] = d4;
        if (d4.x >= 0) atomicAdd(&hist[d4.x >> BSH], 1);
        if (d4.y >= 0) atomicAdd(&hist[d4.y >> BSH], 1);
        if (d4.z >= 0) atomicAdd(&hist[d4.z >> BSH], 1);
        if (d4.w >= 0) atomicAdd(&hist[d4.w >> BSH], 1);
    }
    __syncthreads();
    for (int b = t; b < nb; b += 256) {
        int v = hist[b];
        base[b] = v ? atomicAdd(&bcursor[b], v) : 0;
        hist[b] = 0;   // reset for rank pass
    }
    __syncthreads();
#pragma unroll
    for (int i = 0; i < 8; i++) {
        int li = t + i * 256;
        int d = eD[li];
        if (d >= 0) {
            int b = d >> BSH;
            int r = atomicAdd(&hist[b], 1);
            staged[base[b] + r] = make_int2(eS[li], d);
        }
    }
}

// ---------- per-bucket fused CSR: count+scan -> meta/dinv, then fill rec ----------
__global__ __launch_bounds__(256) void fine_csr_kernel(
    const int2* __restrict__ staged, const int* __restrict__ bstart,
    const int* __restrict__ bcnt, int4* __restrict__ meta,
    float* __restrict__ dinv, int* __restrict__ rec, int n) {
    __shared__ int lcnt[512];
    __shared__ int tsum[256];
    int b = blockIdx.x;
    int t = threadIdx.x;
    lcnt[t] = 0;
    lcnt[t + 256] = 0;
    __syncthreads();
    int s0 = bstart[b];
    int m = bcnt[b];
    for (int i = t; i < m; i += 256)
        atomicAdd(&lcnt[staged[s0 + i].y & 511], 1);
    __syncthreads();
    int v0 = lcnt[2 * t];
    int v1 = lcnt[2 * t + 1];
    int tot = v0 + v1;
    tsum[t] = tot;
    __syncthreads();
    int x = tot;
    for (int off = 1; off < 256; off <<= 1) {
        int y = (t >= off) ? tsum[t - off] : 0;
        __syncthreads();
        x += y;
        tsum[t] = x;
        __syncthreads();
    }
    int excl = x - tot;
    int node = (b << BSH) + 2 * t;
    if (node < n) {
        float di = rsqrtf((float)v0 + 1.0f);
        dinv[node] = di;
        meta[node] = make_int4(s0 + excl, v0, __float_as_int(di), __float_as_int(di * di));
    }
    if (node + 1 < n) {
        float di = rsqrtf((float)v1 + 1.0f);
        dinv[node + 1] = di;
        meta[node + 1] = make_int4(s0 + excl + v0, v1, __float_as_int(di), __float_as_int(di * di));
    }
    // repurpose lcnt as absolute cursors
    lcnt[2 * t] = s0 + excl;
    lcnt[2 * t + 1] = s0 + excl + v0;
    __syncthreads();
    // fill: rec[pos] = src (bucket segment is L2-hot from count pass)
    for (int i = t; i < m; i += 256) {
        int2 ed = staged[s0 + i];
        int li = ed.y & 511;
        int pos = atomicAdd(&lcnt[li], 1);
        rec[pos] = ed.x;
    }
}

// ---------- bf16 MFMA GEMM: Cq[n,COLS](bf16) = X[n,128] @ W[128,COLS] ----------
template <int COLS, bool XF32>
__global__ __launch_bounds__(256) void gemm_mfma(const void* __restrict__ Xv,
                                                 const float* __restrict__ W,
                                                 uint* __restrict__ Cq, int n) {
    __shared__ ushort sX[64 * 128];
    __shared__ ushort sWT[COLS * 128];
    int t = threadIdx.x;
    int rbase = blockIdx.x * 64;

    if (XF32) {
        const float* X = (const float*)Xv;
#pragma unroll
        for (int i = 0; i < 8; i++) {
            int f = t + 256 * i;
            int r = f >> 5;
            int c4 = f & 31;
            float4 v = make_float4(0.f, 0.f, 0.f, 0.f);
            int gr = rbase + r;
            if (gr < n) v = *(const float4*)(X + (size_t)gr * 128 + c4 * 4);
            uint lo = pack_bf16(v.x, v.y);
            uint hi = pack_bf16(v.z, v.w);
            int chunk = c4 >> 1;
            int sub = (c4 & 1) * 4;
            int off = r * 128 + (((chunk ^ (r & 15)) << 3) + sub);
            *(uint2*)&sX[off] = make_uint2(lo, hi);
        }
    } else {
        const ushort* X = (const ushort*)Xv;
#pragma unroll
        for (int i = 0; i < 4; i++) {
            int f = t + 256 * i;
            int r = f >> 4;
            int chunk = f & 15;
            uint4 v = make_uint4(0, 0, 0, 0);
            int gr = rbase + r;
            if (gr < n) v = *(const uint4*)(X + (size_t)gr * 128 + chunk * 8);
            int off = r * 128 + ((chunk ^ (r & 15)) << 3);
            *(uint4*)&sX[off] = v;
        }
    }
    {
        constexpr int UNITS = 64 * (COLS / 4);
        constexpr int PER_T = UNITS / 256;
#pragma unroll
        for (int i = 0; i < PER_T; i++) {
            int u = t + 256 * i;
            int kp = u / (COLS / 4);
            int n4 = u % (COLS / 4);
            int k = kp * 2;
            float4 w0 = *(const float4*)(W + (size_t)k * COLS + n4 * 4);
            float4 w1 = *(const float4*)(W + (size_t)(k + 1) * COLS + n4 * 4);
            int chunk = k >> 3;
            int sub = k & 7;
            const float* a0 = (const float*)&w0;
            const float* a1 = (const float*)&w1;
#pragma unroll
            for (int j = 0; j < 4; j++) {
                int nn = n4 * 4 + j;
                uint pk = pack_bf16(a0[j], a1[j]);
                int off = nn * 128 + (((chunk ^ (nn & 15)) << 3) + sub);
                *(uint*)&sWT[off] = pk;
            }
        }
    }
    __syncthreads();

    int lane = t & 63;
    int wave = t >> 6;
    int m = lane & 15;
    int q = lane >> 4;
    int r0 = wave * 16;

    floatx4 acc[COLS / 16];
#pragma unroll
    for (int c = 0; c < COLS / 16; c++) acc[c] = (floatx4){0.f, 0.f, 0.f, 0.f};

#pragma unroll
    for (int ks = 0; ks < 4; ks++) {
        int rr = r0 + m;
        int ca = (ks * 4 + q) ^ (rr & 15);
        short8 afrag = *(const short8*)&sX[rr * 128 + (ca << 3)];
#pragma unroll
        for (int c = 0; c < COLS / 16; c++) {
            int nn = c * 16 + m;
            int cb = (ks * 4 + q) ^ (nn & 15);
            short8 bfrag = *(const short8*)&sWT[nn * 128 + (cb << 3)];
            acc[c] = __builtin_amdgcn_mfma_f32_16x16x32_bf16(bfrag, afrag, acc[c], 0, 0, 0);
        }
    }

    int gr = rbase + r0 + m;
    if (gr < n) {
#pragma unroll
        for (int c = 0; c < COLS / 16; c++) {
            uint2 pk;
            pk.x = pack_bf16(acc[c][0], acc[c][1]);
            pk.y = pack_bf16(acc[c][2], acc[c][3]);
            *(uint2*)&Cq[(size_t)gr * (COLS / 2) + c * 8 + q * 2] = pk;
        }
    }
}

// ---------- FUSED: aggregate layer-1 (D=128) + GEMM2 (128->64) ----------
// 512 threads = 16 half-waves = 16 nodes/block. Each half-wave aggregates
// one node's row (32 lanes x uint2 = 256B). g tile -> LDS bf16 (swizzled),
// then 4 waves compute h2 = g @ W2 via MFMA 16x16x32 and store bf16.
__global__ __launch_bounds__(512) void agg128_mm64(
    const uint* __restrict__ hq, const int* __restrict__ rec,
    const int4* __restrict__ meta, const float* __restrict__ dinv,
    const float* __restrict__ bias, const float* __restrict__ W2,
    uint* __restrict__ h2q, int n) {
    __shared__ ushort sWT[64 * 128];
    __shared__ ushort sg[16 * 128];
    int t = threadIdx.x;

    // stage W2^T (f32 -> bf16, XOR swizzle) — same pattern as gemm_mfma<64>
#pragma unroll
    for (int i = 0; i < 2; i++) {
        int u = t + 512 * i;          // 0..1023 = (kp, n4)
        int kp = u >> 4;
        int n4 = u & 15;
        int k = kp * 2;
        float4 w0 = *(const float4*)(W2 + (size_t)k * 64 + n4 * 4);
        float4 w1 = *(const float4*)(W2 + (size_t)(k + 1) * 64 + n4 * 4);
        int chunk = k >> 3;
        int sub = k & 7;
        const float* a0f = (const float*)&w0;
        const float* a1f = (const float*)&w1;
#pragma unroll
        for (int j = 0; j < 4; j++) {
            int nn = n4 * 4 + j;
            uint pk = pack_bf16(a0f[j], a1f[j]);
            *(uint*)&sWT[nn * 128 + (((chunk ^ (nn & 15)) << 3) + sub)] = pk;
        }
    }

    int hw = t >> 5;                  // 0..15 local node
    int fl = t & 31;
    int nb0 = blockIdx.x * 16;
    int w = nb0 + hw;
    bool valid = w < n;
    int wsafe = valid ? w : 0;
    const uint2* h2 = (const uint2*)hq;

    int4 mt = meta[wsafe];
    int j0 = mt.x;
    int deg = valid ? mt.y : 0;
    float di = __int_as_float(mt.z);
    float swq = valid ? __int_as_float(mt.w) : 0.f;

    uint2 qs = h2[(size_t)wsafe * 32 + fl];
    float a0 = bf16_lo(qs.x) * swq, a1 = bf16_hi(qs.x) * swq;
    float a2 = bf16_lo(qs.y) * swq, a3 = bf16_hi(qs.y) * swq;

    const int* rp = rec + j0;
    int tt = 0;
    for (; tt + 8 <= deg; tt += 8) {
        uint2 q[8]; float wf[8];
#pragma unroll
        for (int u = 0; u < 8; u++) {
            int s = rp[tt + u];
            wf[u] = dinv[s] * di;
            q[u] = h2[(size_t)s * 32 + fl];
        }
#pragma unroll
        for (int u = 0; u < 8; u++) {
            a0 += bf16_lo(q[u].x) * wf[u]; a1 += bf16_hi(q[u].x) * wf[u];
            a2 += bf16_lo(q[u].y) * wf[u]; a3 += bf16_hi(q[u].y) * wf[u];
        }
    }
    for (; tt + 2 <= deg; tt += 2) {
        int s0i = rp[tt], s1i = rp[tt + 1];
        float w0v = dinv[s0i] * di, w1v = dinv[s1i] * di;
        uint2 q0 = h2[(size_t)s0i * 32 + fl];
        uint2 q1 = h2[(size_t)s1i * 32 + fl];
        a0 += bf16_lo(q0.x) * w0v + bf16_lo(q1.x) * w1v;
        a1 += bf16_hi(q0.x) * w0v + bf16_hi(q1.x) * w1v;
        a2 += bf16_lo(q0.y) * w0v + bf16_lo(q1.y) * w1v;
        a3 += bf16_hi(q0.y) * w0v + bf16_hi(q1.y) * w1v;
    }
    if (tt < deg) {
        int s = rp[tt];
        float wv = dinv[s] * di;
        uint2 q = h2[(size_t)s * 32 + fl];
        a0 += bf16_lo(q.x) * wv; a1 += bf16_hi(q.x) * wv;
        a2 += bf16_lo(q.y) * wv; a3 += bf16_hi(q.y) * wv;
    }

    // bias + relu -> bf16 -> LDS g tile (same swizzle as gemm_mfma staging)
    float4 bb = *(const float4*)&bias[4 * fl];
    float o0 = fmaxf(a0 + bb.x, 0.f);
    float o1 = fmaxf(a1 + bb.y, 0.f);
    float o2 = fmaxf(a2 + bb.z, 0.f);
    float o3 = fmaxf(a3 + bb.w, 0.f);
    {
        int chunk = fl >> 1;
        int sub = (fl & 1) * 4;
        *(uint2*)&sg[hw * 128 + (((chunk ^ hw) << 3) + sub)] =
            make_uint2(pack_bf16(o0, o1), pack_bf16(o2, o3));
    }
    __syncthreads();

    // h2 = g @ W2 : 16 rows x 64 cols, 4 waves each own one 16-col chunk
    int wave = t >> 6;
    int lane = t & 63;
    if (wave < 4) {
        int m = lane & 15;
        int q = lane >> 4;
        floatx4 acc = (floatx4){0.f, 0.f, 0.f, 0.f};
#pragma unroll
        for (int ks = 0; ks < 4; ks++) {
            int ca = (ks * 4 + q) ^ m;
            short8 afrag = *(const short8*)&sg[m * 128 + (ca << 3)];
            int nn = wave * 16 + m;
            int cb = (ks * 4 + q) ^ (nn & 15);
            short8 bfrag = *(const short8*)&sWT[nn * 128 + (cb << 3)];
            acc = __builtin_amdgcn_mfma_f32_16x16x32_bf16(bfrag, afrag, acc, 0, 0, 0);
        }
        int gr = nb0 + m;
        if (gr < n) {
            uint2 pk;
            pk.x = pack_bf16(acc[0], acc[1]);
            pk.y = pack_bf16(acc[2], acc[3]);
            *(uint2*)&h2q[(size_t)gr * 32 + wave * 8 + q * 2] = pk;
        }
    }
}

// ---------- pull aggregation, D=64 (bf16 in, f32 out), half-wave/node ----------
__global__ __launch_bounds__(256) void aggregate64q(
    const uint* __restrict__ hq, const int* __restrict__ rec,
    const int4* __restrict__ meta, const float* __restrict__ dinv,
    const float* __restrict__ bias, float* __restrict__ out, int n) {
    int w = (int)((blockIdx.x * blockDim.x + threadIdx.x) >> 5);
    if (w >= n) return;
    int fl = threadIdx.x & 31;

    int4 mt = meta[w];
    int j0 = mt.x;
    int deg = mt.y;
    float di = __int_as_float(mt.z);
    float swq = __int_as_float(mt.w);

    uint qs = hq[(size_t)w * 32 + fl];
    float a0 = bf16_lo(qs) * swq;
    float a1 = bf16_hi(qs) * swq;

    const int* rp = rec + j0;
    int t = 0;
    for (; t + 8 <= deg; t += 8) {
        uint q[8]; float wf[8];
#pragma unroll
        for (int u = 0; u < 8; u++) {
            int s = rp[t + u];
            wf[u] = dinv[s] * di;
            q[u] = hq[(size_t)s * 32 + fl];
        }
#pragma unroll
        for (int u = 0; u < 8; u++) {
            a0 += bf16_lo(q[u]) * wf[u];
            a1 += bf16_hi(q[u]) * wf[u];
        }
    }
    for (; t + 2 <= deg; t += 2) {
        int s0i = rp[t], s1i = rp[t + 1];
        float w0v = dinv[s0i] * di, w1v = dinv[s1i] * di;
        uint q0 = hq[(size_t)s0i * 32 + fl];
        uint q1 = hq[(size_t)s1i * 32 + fl];
        a0 += bf16_lo(q0) * w0v + bf16_lo(q1) * w1v;
        a1 += bf16_hi(q0) * w0v + bf16_hi(q1) * w1v;
    }
    if (t < deg) {
        int s = rp[t];
        float wv = dinv[s] * di;
        uint q = hq[(size_t)s * 32 + fl];
        a0 += bf16_lo(q) * wv;
        a1 += bf16_hi(q) * wv;
    }

    float2 bb = *(const float2*)&bias[2 * fl];
    float2 o;
    o.x = a0 + bb.x;
    o.y = a1 + bb.y;
    ((float2*)out)[(size_t)w * 32 + fl] = o;
}

extern "C" void kernel_launch(void* const* d_in, const int* in_sizes, int n_in,
                              void* d_out, int out_size, void* d_ws, size_t ws_size,
                              hipStream_t stream) {
    const float* x = (const float*)d_in[0];
    const int* edge = (const int*)d_in[1];
    const float* W1 = (const float*)d_in[2];
    const float* b1 = (const float*)d_in[3];
    const float* W2 = (const float*)d_in[4];
    const float* b2 = (const float*)d_in[5];

    const int N = in_sizes[0] / 128;
    const int E = in_sizes[1] / 2;
    const int* src = edge;
    const int* dst = edge + E;
    const int NB = (N + (1 << BSH) - 1) >> BSH;   // coarse buckets (<= 256)

    // workspace carve-up (all chunks 16B-aligned for these sizes)
    char* p = (char*)d_ws;
    int* bcnt = (int*)p;      p += NBMAX * 4;
    int* bstart = (int*)p;    p += NBMAX * 4;
    int* bcursor = (int*)p;   p += NBMAX * 4;
    float* dinv = (float*)p;  p += (size_t)N * 4;
    int4* meta = (int4*)p;    p += (size_t)N * 16;      // (start, deg, dinv, dinv^2)
    int* rec = (int*)p;       p += (size_t)E * 4;       // src per edge (CSR by dst)
    int2* staged = (int2*)p;  p += (size_t)E * 8;       // (src,dst) bucket-grouped
    uint* hq = (uint*)p;      p += (size_t)N * 64 * 4;  // h = x@W1, bf16 pairs
    uint* h2q = (uint*)p;     p += (size_t)N * 32 * 4;  // h2, bf16 (64 feats)

    float* out = (float*)d_out;
    const int eblocks = (E + 2047) / 2048;

    // CSR build (two-level bucketed, zero per-node global atomics)
    (void)hipMemsetAsync(bcnt, 0, NBMAX * 4, stream);
    bucket_hist_kernel<<<eblocks, 256, 0, stream>>>(dst, bcnt, E, NB);
    bucket_scan<<<1, NBMAX, 0, stream>>>(bcnt, bstart, bcursor, NB);
    partition_kernel<<<eblocks, 256, 0, stream>>>(src, dst, bcursor, staged, E, NB);
    fine_csr_kernel<<<NB, 256, 0, stream>>>(staged, bstart, bcnt, meta, dinv, rec, N);

    const int gblocks = (N + 63) / 64;

    // layer 1 GEMM: h = x @ W1 (bf16)
    gemm_mfma<128, true><<<gblocks, 256, 0, stream>>>(x, W1, hq, N);
    // fused: g = relu(Anorm@h + b1); h2 = g @ W2  (writes h2 bf16 directly)
    agg128_mm64<<<(N + 15) / 16, 512, 0, stream>>>(hq, rec, meta, dinv, b1, W2, h2q, N);
    // layer 2 aggregation: out = Anorm @ h2 + b2
    aggregate64q<<<(N + 7) / 8, 256, 0, stream>>>(h2q, rec, meta, dinv, b2, out, N);
}